// Round 11
// baseline (484.123 us; speedup 1.0000x reference)
//
#include <hip/hip_runtime.h>
#include <hip/hip_bf16.h>

// GQA forward, round 10: split-K all-register flash attention. Round 9 structure
// (fragment-order Q/K/V, no LDS, no barriers, in-register P via permlane swaps)
// + keys split into 2 halves per block (1024 blocks -> 4 waves/SIMD) + combine
// kernel + s_setprio around MFMA clusters.
// B=2, S=2048, HIDDEN=1024, 16 heads x 64 dim, RoPE over full hidden (half=512).
// ws (ushort elems): q k v ao xb wall kfrag (7 x 4M = 56 MB) + ml (1 MB).
// Opart[2] overlays k,v (dead during flash); qfrag=xb, vfrag=q.

constexpr int Bb  = 2;
constexpr int Ss  = 2048;
constexpr int Hh  = 1024;
constexpr int NHh = 16;
constexpr int Mm  = Bb * Ss;   // 4096 rows

typedef __attribute__((ext_vector_type(8))) unsigned short ushort8;
typedef __attribute__((ext_vector_type(8))) short short8;
typedef __attribute__((ext_vector_type(4))) float f32x4;
typedef __attribute__((ext_vector_type(4))) unsigned int u32x4;

__device__ __forceinline__ unsigned short f2bf(float f) {
    unsigned int u = __float_as_uint(f);
    u += 0x7fffu + ((u >> 16) & 1u);
    return (unsigned short)(u >> 16);
}
__device__ __forceinline__ float bf2f(unsigned short h) {
    return __uint_as_float(((unsigned int)h) << 16);
}
__device__ __forceinline__ void gload16(const void* g, void* l) {
    __builtin_amdgcn_global_load_lds(
        (const __attribute__((address_space(1))) unsigned int*)g,
        (__attribute__((address_space(3))) unsigned int*)l, 16, 0, 0);
}

// ---------------- fp32 -> bf16 convert (x, Wq|Wk|Wv|Wo into one block) ----------
__global__ __launch_bounds__(256) void convert_k(
    const float* __restrict__ x,
    const float* __restrict__ Wq, const float* __restrict__ Wk,
    const float* __restrict__ Wv, const float* __restrict__ Wo,
    unsigned short* __restrict__ xb, unsigned short* __restrict__ wall)
{
    size_t e = ((size_t)blockIdx.x * 256 + threadIdx.x) << 3;
    const float* s; unsigned short* d;
    if (e < (size_t)Mm * Hh) {
        s = x + e; d = xb + e;
    } else {
        size_t f = e - (size_t)Mm * Hh;
        int t = (int)(f >> 20);
        const float* w = (t == 0) ? Wq : (t == 1) ? Wk : (t == 2) ? Wv : Wo;
        s = w + (f & 1048575);
        d = wall + f;
    }
    float4 a = *(const float4*)s;
    float4 b = *(const float4*)(s + 4);
    ushort8 o;
    o[0] = f2bf(a.x); o[1] = f2bf(a.y); o[2] = f2bf(a.z); o[3] = f2bf(a.w);
    o[4] = f2bf(b.x); o[5] = f2bf(b.y); o[6] = f2bf(b.z); o[7] = f2bf(b.w);
    *(ushort8*)d = o;
}

// ---------------- bf16 MFMA GEMM core (unchanged) --------------------------------
#define GEMM_BODY(ATYPE_PTR, WPTR, K0MAX)                                          \
    __shared__ unsigned short As[128 * 64];                                        \
    __shared__ unsigned short Bs[128 * 64];                                        \
    const int tid  = threadIdx.x;                                                  \
    const int lane = tid & 63;                                                     \
    const int w    = tid >> 6;                                                     \
    const int wr   = w >> 1, wc = w & 1;                                           \
    const int l16  = lane & 15, g = lane >> 4;                                     \
    const int R0   = blockIdx.x * 128;                                             \
    char* asb = (char*)As; char* bsb = (char*)Bs;                                  \
    f32x4 acc[4][4] = {};                                                          \
    for (int k0 = 0; k0 < K0MAX; k0 += 64) {                                       \
        _Pragma("unroll")                                                          \
        for (int it = 0; it < 4; ++it) {                                           \
            int sbase = w * 4096 + it * 1024;                                      \
            int boff  = sbase + lane * 16;                                         \
            int r     = boff >> 7;                                                 \
            int c     = (boff >> 4) & 7;                                           \
            int col   = k0 + ((c ^ (r & 7)) << 3);                                 \
            gload16(&ATYPE_PTR[(size_t)(R0 + r) * 1024 + col], asb + sbase);       \
            gload16(&WPTR[(size_t)(gn + r) * 1024 + col], bsb + sbase);            \
        }                                                                          \
        __syncthreads();                                                           \
        short8 bfrag[4][2];                                                        \
        _Pragma("unroll")                                                          \
        for (int u = 0; u < 4; ++u) {                                              \
            int row = wc * 64 + u * 16 + l16;                                      \
            _Pragma("unroll")                                                      \
            for (int s = 0; s < 2; ++s)                                            \
                bfrag[u][s] = *(const short8*)(bsb + row * 128 +                   \
                               ((s * 64 + g * 16) ^ ((row & 7) << 4)));            \
        }                                                                          \
        _Pragma("unroll")                                                          \
        for (int t = 0; t < 4; ++t) {                                              \
            int row = wr * 64 + t * 16 + l16;                                      \
            short8 af[2];                                                          \
            _Pragma("unroll")                                                      \
            for (int s = 0; s < 2; ++s)                                            \
                af[s] = *(const short8*)(asb + row * 128 +                         \
                         ((s * 64 + g * 16) ^ ((row & 7) << 4)));                  \
            _Pragma("unroll")                                                      \
            for (int u = 0; u < 4; ++u) {                                          \
                acc[t][u] = __builtin_amdgcn_mfma_f32_16x16x32_bf16(af[0], bfrag[u][0], acc[t][u], 0, 0, 0); \
                acc[t][u] = __builtin_amdgcn_mfma_f32_16x16x32_bf16(af[1], bfrag[u][1], acc[t][u], 0, 0, 0); \
            }                                                                      \
        }                                                                          \
        __syncthreads();                                                           \
    }

__global__ __launch_bounds__(256) void gemm_qkv_k(
    const unsigned short* __restrict__ xb, const unsigned short* __restrict__ wall,
    const float* __restrict__ bq, const float* __restrict__ bk, const float* __restrict__ bv,
    unsigned short* __restrict__ q, unsigned short* __restrict__ k2,
    unsigned short* __restrict__ v)
{
    const int gn = blockIdx.y * 128;
    GEMM_BODY(xb, wall, 1024)

    const int sel = gn >> 10;
    const int n0  = gn & 1023;
    const float* bias = (sel == 0) ? bq : (sel == 1) ? bk : bv;
    unsigned short* outp = (sel == 0) ? q : (sel == 1) ? k2 : v;
    // Pre-scale q by (1/8)*log2e: q feeds only QK^T; scale commutes with RoPE.
    const float qs = (sel == 0) ? 0.18033688011112042f : 1.0f;
    #pragma unroll
    for (int u = 0; u < 4; ++u) {
        int coll = wc * 64 + u * 16 + l16;
        float bb = bias[n0 + coll];
        #pragma unroll
        for (int t = 0; t < 4; ++t)
            #pragma unroll
            for (int rr = 0; rr < 4; ++rr) {
                int row = R0 + wr * 64 + t * 16 + g * 4 + rr;
                outp[(size_t)row * 1024 + n0 + coll] = f2bf((acc[t][u][rr] + bb) * qs);
            }
    }
}

__global__ __launch_bounds__(256) void gemm_out_k(
    const unsigned short* __restrict__ ao, const unsigned short* __restrict__ wo,
    const float* __restrict__ bo, float* __restrict__ out)
{
    const int gn = blockIdx.y * 128;
    GEMM_BODY(ao, wo, 1024)

    #pragma unroll
    for (int u = 0; u < 4; ++u) {
        int coll = wc * 64 + u * 16 + l16;
        float bb = bo[gn + coll];
        #pragma unroll
        for (int t = 0; t < 4; ++t)
            #pragma unroll
            for (int rr = 0; rr < 4; ++rr) {
                int row = R0 + wr * 64 + t * 16 + g * 4 + rr;
                out[(size_t)row * 1024 + gn + coll] = acc[t][u][rr] + bb;
            }
    }
}

// ---------------- RoPE + fragment materialization for q and k --------------------
__global__ __launch_bounds__(256) void rope_frag_k(
    const unsigned short* __restrict__ qin, const unsigned short* __restrict__ kin,
    unsigned short* __restrict__ qfrag, unsigned short* __restrict__ kfrag)
{
    __shared__ unsigned short Ld[2][64][72];
    const int kt = blockIdx.x;        // 0..31
    const int hp = blockIdx.y;        // 0..7
    const int zz = blockIdx.z;        // bit0 = bz, bit1 = sel
    const int bz = zz & 1, sel = zz >> 1;
    const unsigned short* src = sel ? kin : qin;
    unsigned short* dstf = sel ? kfrag : qfrag;

    const int t   = threadIdx.x;
    const int r   = t & 63;
    const int c16 = (t >> 6) << 4;    // 0,16,32,48
    const int pos = kt * 64 + r;
    const size_t rowb = (size_t)(bz * Ss + pos) * 1024;

    ushort8 A0 = *(const ushort8*)&src[rowb + hp * 64 + c16];
    ushort8 A1 = *(const ushort8*)&src[rowb + hp * 64 + c16 + 8];
    ushort8 B0 = *(const ushort8*)&src[rowb + (hp + 8) * 64 + c16];
    ushort8 B1 = *(const ushort8*)&src[rowb + (hp + 8) * 64 + c16 + 8];

    #pragma unroll
    for (int i = 0; i < 16; ++i) {
        int d = c16 + i;
        float jj  = (float)(hp * 64 + d);
        float inv = exp2f(jj * -0.0259525632621414f);   // 10000^(-j/512)
        float ang = (float)pos * inv;
        float sn, cs;
        __sincosf(ang, &sn, &cs);
        unsigned short ua = (i < 8) ? A0[i] : A1[i - 8];
        unsigned short ub = (i < 8) ? B0[i] : B1[i - 8];
        float a = bf2f(ua), b = bf2f(ub);
        Ld[0][r][d] = f2bf(a * cs - b * sn);   // head hp   (low half j)
        Ld[1][r][d] = f2bf(b * cs + a * sn);   // head hp+8 (high half j+512)
    }
    __syncthreads();

    #pragma unroll
    for (int cc = 0; cc < 4; ++cc) {
        int c    = t * 4 + cc;            // 0..1023
        int hh   = c >> 9;                // head select
        int ci   = c & 511;               // chunk within head tile (0..511)
        int blk  = ci >> 7, s2 = (ci >> 6) & 1, lane2 = ci & 63;
        int gg = lane2 >> 4, ll = lane2 & 15;
        ushort8 o = *(const ushort8*)&Ld[hh][blk * 16 + ll][s2 * 32 + gg * 8];
        size_t base = (size_t)(bz * 16 + hp + hh * 8) * 131072 + (size_t)kt * 4096;
        *(ushort8*)&dstf[base + (size_t)ci * 8] = o;
    }
}

// ---------------- V fragment materialization (B-operand / V^T order) -------------
__global__ __launch_bounds__(256) void fragify_v_k(
    const unsigned short* __restrict__ v, unsigned short* __restrict__ vfrag)
{
    __shared__ unsigned short Ld[64][72];
    const int kt = blockIdx.x, bh = blockIdx.y;   // bh = bz*16+h
    const int bz = bh >> 4, h = bh & 15;
    const int t = threadIdx.x;
    const int r = t & 63, c0 = (t >> 6) << 4;
    const unsigned short* srcp = &v[(size_t)(bz * Ss + kt * 64 + r) * 1024 + h * 64 + c0];
    *(ushort8*)&Ld[r][c0]     = *(const ushort8*)srcp;
    *(ushort8*)&Ld[r][c0 + 8] = *(const ushort8*)(srcp + 8);
    __syncthreads();

    #pragma unroll
    for (int cc = 0; cc < 2; ++cc) {
        int c = t * 2 + cc;               // 0..511
        int dt4 = c >> 7, ks = (c >> 6) & 1, lane2 = c & 63;
        int gg = lane2 >> 4, ll = lane2 & 15;
        ushort8 o;
        #pragma unroll
        for (int e = 0; e < 8; ++e)
            o[e] = Ld[ks * 32 + gg * 8 + e][dt4 * 16 + ll];
        *(ushort8*)&vfrag[(size_t)bh * 131072 + (size_t)kt * 4096 + (size_t)c * 8] = o;
    }
}

// ---------------- Flash attention: all-register, split-K halves ------------------
#define FLASH_ITER(KC, KN, KT)                                                     \
    {                                                                              \
        const int ktn = kt0 + ((((KT) - kt0) + 1) & 15);                           \
        _Pragma("unroll")                                                          \
        for (int i = 0; i < 8; ++i)                                                \
            KN[i] = *(const short8*)&kfb[(size_t)ktn * 4096 + i * 512 + lane * 8]; \
        _Pragma("unroll")                                                          \
        for (int i = 0; i < 8; ++i)                                                \
            VV[i] = *(const short8*)&vfb[(size_t)(KT) * 4096 + i * 512 + lane * 8];\
        int mk[4][4];                                                              \
        _Pragma("unroll")                                                          \
        for (int k4 = 0; k4 < 4; ++k4)                                             \
            *(int4*)&mk[k4][0] =                                                   \
                *(const int4*)&mask[bz * Ss + (KT) * 64 + k4 * 16 + g * 4];        \
        f32x4 S[2][4];                                                             \
        _Pragma("unroll")                                                          \
        for (int t = 0; t < 2; ++t)                                                \
            _Pragma("unroll")                                                      \
            for (int k4 = 0; k4 < 4; ++k4) S[t][k4] = (f32x4)0.f;                  \
        __builtin_amdgcn_s_setprio(1);                                             \
        _Pragma("unroll")                                                          \
        for (int k4 = 0; k4 < 4; ++k4)                                             \
            _Pragma("unroll")                                                      \
            for (int t = 0; t < 2; ++t) {                                          \
                S[t][k4] = __builtin_amdgcn_mfma_f32_16x16x32_bf16(                \
                    KC[k4 * 2 + 0], qf[t][0], S[t][k4], 0, 0, 0);                  \
                S[t][k4] = __builtin_amdgcn_mfma_f32_16x16x32_bf16(                \
                    KC[k4 * 2 + 1], qf[t][1], S[t][k4], 0, 0, 0);                  \
            }                                                                      \
        __builtin_amdgcn_s_setprio(0);                                             \
        _Pragma("unroll")                                                          \
        for (int t = 0; t < 2; ++t)                                                \
            _Pragma("unroll")                                                      \
            for (int k4 = 0; k4 < 4; ++k4)                                         \
                _Pragma("unroll")                                                  \
                for (int r = 0; r < 4; ++r)                                        \
                    S[t][k4][r] = mk[k4][r] ? S[t][k4][r] : -1e30f;                \
        float rm[2];                                                               \
        _Pragma("unroll")                                                          \
        for (int t = 0; t < 2; ++t) {                                              \
            float m0 = fmaxf(fmaxf(S[t][0][0], S[t][0][1]), fmaxf(S[t][0][2], S[t][0][3])); \
            float m1 = fmaxf(fmaxf(S[t][1][0], S[t][1][1]), fmaxf(S[t][1][2], S[t][1][3])); \
            float m2 = fmaxf(fmaxf(S[t][2][0], S[t][2][1]), fmaxf(S[t][2][2], S[t][2][3])); \
            float m3 = fmaxf(fmaxf(S[t][3][0], S[t][3][1]), fmaxf(S[t][3][2], S[t][3][3])); \
            float m  = fmaxf(fmaxf(m0, m1), fmaxf(m2, m3));                        \
            m = fmaxf(m, __shfl_xor(m, 16));                                       \
            m = fmaxf(m, __shfl_xor(m, 32));                                       \
            rm[t] = m;                                                             \
        }                                                                          \
        bool grow = (rm[0] > mrow[0] + 10.0f) || (rm[1] > mrow[1] + 10.0f);        \
        if (__any((int)grow)) {                                                    \
            float mn0 = fmaxf(mrow[0], rm[0]);                                     \
            float mn1 = fmaxf(mrow[1], rm[1]);                                     \
            float rs0 = exp2f(mrow[0] - mn0);                                      \
            float rs1 = exp2f(mrow[1] - mn1);                                      \
            mrow[0] = mn0; mrow[1] = mn1;                                          \
            _Pragma("unroll")                                                      \
            for (int r = 0; r < 4; ++r) {                                          \
                float f0 = __shfl(rs0, g * 4 + r);                                 \
                float f1 = __shfl(rs1, g * 4 + r);                                 \
                _Pragma("unroll")                                                  \
                for (int dt = 0; dt < 4; ++dt) { O[0][dt][r] *= f0; O[1][dt][r] *= f1; } \
                Osum[0][r] *= f0; Osum[1][r] *= f1;                                \
            }                                                                      \
        }                                                                          \
        _Pragma("unroll")                                                          \
        for (int t = 0; t < 2; ++t) {                                              \
            unsigned int U[4][2];                                                  \
            _Pragma("unroll")                                                      \
            for (int k4 = 0; k4 < 4; ++k4) {                                       \
                float p0 = exp2f(S[t][k4][0] - mrow[t]);                           \
                float p1 = exp2f(S[t][k4][1] - mrow[t]);                           \
                float p2 = exp2f(S[t][k4][2] - mrow[t]);                           \
                float p3 = exp2f(S[t][k4][3] - mrow[t]);                           \
                asm("v_cvt_pk_bf16_f32 %0, %1, %2" : "=v"(U[k4][0]) : "v"(p0), "v"(p1)); \
                asm("v_cvt_pk_bf16_f32 %0, %1, %2" : "=v"(U[k4][1]) : "v"(p2), "v"(p3)); \
            }                                                                      \
            asm("v_permlane32_swap_b32 %0, %1" : "+v"(U[0][0]), "+v"(U[1][0]));    \
            asm("v_permlane32_swap_b32 %0, %1" : "+v"(U[0][1]), "+v"(U[1][1]));    \
            asm("v_permlane32_swap_b32 %0, %1" : "+v"(U[2][0]), "+v"(U[3][0]));    \
            asm("v_permlane32_swap_b32 %0, %1" : "+v"(U[2][1]), "+v"(U[3][1]));    \
            asm("v_permlane16_swap_b32 %0, %1" : "+v"(U[0][0]), "+v"(U[1][0]));    \
            asm("v_permlane16_swap_b32 %0, %1" : "+v"(U[0][1]), "+v"(U[1][1]));    \
            asm("v_permlane16_swap_b32 %0, %1" : "+v"(U[2][0]), "+v"(U[3][0]));    \
            asm("v_permlane16_swap_b32 %0, %1" : "+v"(U[2][1]), "+v"(U[3][1]));    \
            __builtin_amdgcn_s_setprio(1);                                         \
            _Pragma("unroll")                                                      \
            for (int ks = 0; ks < 2; ++ks) {                                       \
                u32x4 gp;                                                          \
                gp[0] = U[2 * ks][0]; gp[1] = U[2 * ks][1];                        \
                gp[2] = U[2 * ks + 1][0]; gp[3] = U[2 * ks + 1][1];                \
                short8 pf = __builtin_bit_cast(short8, gp);                        \
                Osum[t] = __builtin_amdgcn_mfma_f32_16x16x32_bf16(pf, ones, Osum[t], 0, 0, 0); \
                _Pragma("unroll")                                                  \
                for (int dt = 0; dt < 4; ++dt)                                     \
                    O[t][dt] = __builtin_amdgcn_mfma_f32_16x16x32_bf16(            \
                        pf, VV[dt * 2 + ks], O[t][dt], 0, 0, 0);                   \
            }                                                                      \
            __builtin_amdgcn_s_setprio(0);                                         \
        }                                                                          \
    }

__global__ __launch_bounds__(256, 4) void flash_k(
    const unsigned short* __restrict__ qfrag, const unsigned short* __restrict__ kfrag,
    const unsigned short* __restrict__ vfrag, const int* __restrict__ mask,
    unsigned short* __restrict__ opart, float2* __restrict__ ml)
{
    // Bijective XCD remap: 1024 blocks = 8 XCDs x (4 (h,bz) groups x 16 qb x 2 half).
    const int F   = blockIdx.x;
    const int xcd = F & 7, j = F >> 3;          // j: 0..127
    const int grp = xcd * 4 + (j >> 5);         // 0..31
    const int rem = j & 31;
    const int qb  = rem >> 1;
    const int half = rem & 1;
    const int h   = grp & 15;
    const int bz  = grp >> 4;
    const int kt0 = half * 16;

    const int tid  = threadIdx.x;
    const int lane = tid & 63;
    const int w    = tid >> 6;
    const int l16  = lane & 15;
    const int g    = lane >> 4;

    const size_t fb = (size_t)(bz * 16 + h) * 131072;
    const unsigned short* kfb = kfrag + fb;
    const unsigned short* vfb = vfrag + fb;
    const unsigned short* qfb = qfrag + fb;

    // Q fragments (pre-scaled): blk16 = qb*8 + w*2 + t
    short8 qf[2][2];
    #pragma unroll
    for (int t = 0; t < 2; ++t)
        #pragma unroll
        for (int s = 0; s < 2; ++s)
            qf[t][s] = *(const short8*)&qfb[(size_t)(qb * 8 + w * 2 + t) * 1024
                                            + s * 512 + lane * 8];

    f32x4 O[2][4];
    #pragma unroll
    for (int t = 0; t < 2; ++t)
        #pragma unroll
        for (int d = 0; d < 4; ++d) O[t][d] = (f32x4)0.f;
    f32x4 Osum[2];
    Osum[0] = (f32x4)0.f; Osum[1] = (f32x4)0.f;
    float mrow[2] = {-1.0e4f, -1.0e4f};

    short8 ones;
    #pragma unroll
    for (int e = 0; e < 8; ++e) ones[e] = (short)0x3F80;  // bf16 1.0

    short8 KA[8], KB[8], VV[8];
    #pragma unroll
    for (int i = 0; i < 8; ++i)
        KA[i] = *(const short8*)&kfb[(size_t)kt0 * 4096 + i * 512 + lane * 8];

    for (int kt2 = 0; kt2 < 16; kt2 += 2) {
        FLASH_ITER(KA, KB, kt0 + kt2)
        FLASH_ITER(KB, KA, kt0 + kt2 + 1)
    }

    // ---- epilogue: normalized partial O (bf16) + per-query (m, sum) ----
    const size_t NE = (size_t)Mm * Hh;
    #pragma unroll
    for (int t = 0; t < 2; ++t)
        #pragma unroll
        for (int r = 0; r < 4; ++r) {
            float osum = Osum[t][r];
            float inv  = osum > 0.f ? 1.0f / osum : 0.f;
            float mo   = __shfl(mrow[t], g * 4 + r);   // S-layout m -> O-layout
            int rowl   = qb * 128 + w * 32 + t * 16 + g * 4 + r;   // 0..2047
            size_t ob  = (size_t)half * NE
                       + ((size_t)(bz * Ss + rowl)) * 1024 + h * 64;
            #pragma unroll
            for (int dt = 0; dt < 4; ++dt)
                opart[ob + dt * 16 + l16] = f2bf(O[t][dt][r] * inv);
            if (l16 == 0)
                ml[((half * 2 + bz) * 16 + h) * 2048 + rowl] = make_float2(mo, osum);
        }
}

// ---------------- Combine split-K halves -----------------------------------------
__global__ __launch_bounds__(256) void combine_k(
    const unsigned short* __restrict__ opart, const float2* __restrict__ ml,
    unsigned short* __restrict__ ao)
{
    const size_t NE = (size_t)Mm * Hh;
    int c    = blockIdx.x * 256 + threadIdx.x;   // 0..524287 (4096 rows x 128)
    int row  = c >> 7;                           // bz*2048 + qrow
    int col8 = c & 127;
    int h    = col8 >> 3;
    int bz   = row >> 11, qrow = row & 2047;

    float2 a = ml[((0 * 2 + bz) * 16 + h) * 2048 + qrow];
    float2 b = ml[((1 * 2 + bz) * 16 + h) * 2048 + qrow];
    float M  = fmaxf(a.x, b.x);
    float w1 = exp2f(a.x - M) * a.y;
    float w2 = exp2f(b.x - M) * b.y;
    float tot = w1 + w2;
    float inv = tot > 0.f ? 1.0f / tot : 0.f;
    w1 *= inv; w2 *= inv;

    ushort8 o1 = *(const ushort8*)&opart[(size_t)c * 8];
    ushort8 o2 = *(const ushort8*)&opart[NE + (size_t)c * 8];
    ushort8 o;
    #pragma unroll
    for (int jj = 0; jj < 8; ++jj)
        o[jj] = f2bf(bf2f(o1[jj]) * w1 + bf2f(o2[jj]) * w2);
    *(ushort8*)&ao[(size_t)c * 8] = o;
}

extern "C" void kernel_launch(void* const* d_in, const int* in_sizes, int n_in,
                              void* d_out, int out_size, void* d_ws, size_t ws_size,
                              hipStream_t stream)
{
    const float* x  = (const float*)d_in[0];
    const int*   am = (const int*)d_in[1];
    const float* Wq = (const float*)d_in[2];
    const float* bq = (const float*)d_in[3];
    const float* Wk = (const float*)d_in[4];
    const float* bk = (const float*)d_in[5];
    const float* Wv = (const float*)d_in[6];
    const float* bv = (const float*)d_in[7];
    const float* Wo = (const float*)d_in[8];
    const float* bo = (const float*)d_in[9];
    float* out = (float*)d_out;

    const size_t NE = (size_t)Mm * Hh;           // 4M elems
    unsigned short* q     = (unsigned short*)d_ws;
    unsigned short* k     = q + NE;
    unsigned short* v     = k + NE;
    unsigned short* ao    = v + NE;
    unsigned short* xb    = ao + NE;             // gemm input; reused as qfrag
    unsigned short* wall  = xb + NE;             // [Wq;Wk;Wv;Wo] rows
    unsigned short* wo    = wall + 3u * 1048576u;
    unsigned short* kfrag = wall + 4u * 1048576u;
    unsigned short* qfrag = xb;                  // xb dead after gemm_qkv
    unsigned short* vfrag = q;                   // q dead after rope_frag
    unsigned short* opart = k;                   // k,v dead once frags built (16 MB)
    float2*         ml    = (float2*)(kfrag + 4u * 1048576u);   // +1 MB

    convert_k<<<(2 * NE) / (256 * 8), 256, 0, stream>>>(x, Wq, Wk, Wv, Wo, xb, wall);
    gemm_qkv_k<<<dim3(Mm / 128, 3072 / 128), 256, 0, stream>>>(
        xb, wall, bq, bk, bv, q, k, v);
    rope_frag_k<<<dim3(32, 8, 4), 256, 0, stream>>>(q, k, qfrag, kfrag);
    fragify_v_k<<<dim3(32, 32), 256, 0, stream>>>(v, vfrag);
    flash_k<<<dim3(1024), 256, 0, stream>>>(qfrag, kfrag, vfrag, am, opart, ml);
    combine_k<<<dim3((Mm * 128) / 256), 256, 0, stream>>>(opart, ml, ao);
    gemm_out_k<<<dim3(Mm / 128, Hh / 128), 256, 0, stream>>>(ao, wo, bo, out);
}

// Round 12
// 203.665 us; speedup vs baseline: 2.3771x; 2.3771x over previous
//
#include <hip/hip_runtime.h>
#include <hip/hip_bf16.h>

// GQA forward, round 11: round 10 split-K all-register flash, with the VGPR
// straitjacket removed (__launch_bounds__(256) — no min-waves hint; (256,4)
// forced 64 VGPRs and spilled all K/V/O state to scratch: 1.2 GB writes).
// B=2, S=2048, HIDDEN=1024, 16 heads x 64 dim, RoPE over full hidden (half=512).
// ws (ushort elems): q k v ao xb wall kfrag (7 x 4M = 56 MB) + ml (1 MB).

constexpr int Bb  = 2;
constexpr int Ss  = 2048;
constexpr int Hh  = 1024;
constexpr int NHh = 16;
constexpr int Mm  = Bb * Ss;   // 4096 rows

typedef __attribute__((ext_vector_type(8))) unsigned short ushort8;
typedef __attribute__((ext_vector_type(8))) short short8;
typedef __attribute__((ext_vector_type(4))) float f32x4;
typedef __attribute__((ext_vector_type(4))) unsigned int u32x4;

__device__ __forceinline__ unsigned short f2bf(float f) {
    unsigned int u = __float_as_uint(f);
    u += 0x7fffu + ((u >> 16) & 1u);
    return (unsigned short)(u >> 16);
}
__device__ __forceinline__ float bf2f(unsigned short h) {
    return __uint_as_float(((unsigned int)h) << 16);
}
__device__ __forceinline__ void gload16(const void* g, void* l) {
    __builtin_amdgcn_global_load_lds(
        (const __attribute__((address_space(1))) unsigned int*)g,
        (__attribute__((address_space(3))) unsigned int*)l, 16, 0, 0);
}

// ---------------- fp32 -> bf16 convert (x, Wq|Wk|Wv|Wo into one block) ----------
__global__ __launch_bounds__(256) void convert_k(
    const float* __restrict__ x,
    const float* __restrict__ Wq, const float* __restrict__ Wk,
    const float* __restrict__ Wv, const float* __restrict__ Wo,
    unsigned short* __restrict__ xb, unsigned short* __restrict__ wall)
{
    size_t e = ((size_t)blockIdx.x * 256 + threadIdx.x) << 3;
    const float* s; unsigned short* d;
    if (e < (size_t)Mm * Hh) {
        s = x + e; d = xb + e;
    } else {
        size_t f = e - (size_t)Mm * Hh;
        int t = (int)(f >> 20);
        const float* w = (t == 0) ? Wq : (t == 1) ? Wk : (t == 2) ? Wv : Wo;
        s = w + (f & 1048575);
        d = wall + f;
    }
    float4 a = *(const float4*)s;
    float4 b = *(const float4*)(s + 4);
    ushort8 o;
    o[0] = f2bf(a.x); o[1] = f2bf(a.y); o[2] = f2bf(a.z); o[3] = f2bf(a.w);
    o[4] = f2bf(b.x); o[5] = f2bf(b.y); o[6] = f2bf(b.z); o[7] = f2bf(b.w);
    *(ushort8*)d = o;
}

// ---------------- bf16 MFMA GEMM core (unchanged) --------------------------------
#define GEMM_BODY(ATYPE_PTR, WPTR, K0MAX)                                          \
    __shared__ unsigned short As[128 * 64];                                        \
    __shared__ unsigned short Bs[128 * 64];                                        \
    const int tid  = threadIdx.x;                                                  \
    const int lane = tid & 63;                                                     \
    const int w    = tid >> 6;                                                     \
    const int wr   = w >> 1, wc = w & 1;                                           \
    const int l16  = lane & 15, g = lane >> 4;                                     \
    const int R0   = blockIdx.x * 128;                                             \
    char* asb = (char*)As; char* bsb = (char*)Bs;                                  \
    f32x4 acc[4][4] = {};                                                          \
    for (int k0 = 0; k0 < K0MAX; k0 += 64) {                                       \
        _Pragma("unroll")                                                          \
        for (int it = 0; it < 4; ++it) {                                           \
            int sbase = w * 4096 + it * 1024;                                      \
            int boff  = sbase + lane * 16;                                         \
            int r     = boff >> 7;                                                 \
            int c     = (boff >> 4) & 7;                                           \
            int col   = k0 + ((c ^ (r & 7)) << 3);                                 \
            gload16(&ATYPE_PTR[(size_t)(R0 + r) * 1024 + col], asb + sbase);       \
            gload16(&WPTR[(size_t)(gn + r) * 1024 + col], bsb + sbase);            \
        }                                                                          \
        __syncthreads();                                                           \
        short8 bfrag[4][2];                                                        \
        _Pragma("unroll")                                                          \
        for (int u = 0; u < 4; ++u) {                                              \
            int row = wc * 64 + u * 16 + l16;                                      \
            _Pragma("unroll")                                                      \
            for (int s = 0; s < 2; ++s)                                            \
                bfrag[u][s] = *(const short8*)(bsb + row * 128 +                   \
                               ((s * 64 + g * 16) ^ ((row & 7) << 4)));            \
        }                                                                          \
        _Pragma("unroll")                                                          \
        for (int t = 0; t < 4; ++t) {                                              \
            int row = wr * 64 + t * 16 + l16;                                      \
            short8 af[2];                                                          \
            _Pragma("unroll")                                                      \
            for (int s = 0; s < 2; ++s)                                            \
                af[s] = *(const short8*)(asb + row * 128 +                         \
                         ((s * 64 + g * 16) ^ ((row & 7) << 4)));                  \
            _Pragma("unroll")                                                      \
            for (int u = 0; u < 4; ++u) {                                          \
                acc[t][u] = __builtin_amdgcn_mfma_f32_16x16x32_bf16(af[0], bfrag[u][0], acc[t][u], 0, 0, 0); \
                acc[t][u] = __builtin_amdgcn_mfma_f32_16x16x32_bf16(af[1], bfrag[u][1], acc[t][u], 0, 0, 0); \
            }                                                                      \
        }                                                                          \
        __syncthreads();                                                           \
    }

__global__ __launch_bounds__(256) void gemm_qkv_k(
    const unsigned short* __restrict__ xb, const unsigned short* __restrict__ wall,
    const float* __restrict__ bq, const float* __restrict__ bk, const float* __restrict__ bv,
    unsigned short* __restrict__ q, unsigned short* __restrict__ k2,
    unsigned short* __restrict__ v)
{
    const int gn = blockIdx.y * 128;
    GEMM_BODY(xb, wall, 1024)

    const int sel = gn >> 10;
    const int n0  = gn & 1023;
    const float* bias = (sel == 0) ? bq : (sel == 1) ? bk : bv;
    unsigned short* outp = (sel == 0) ? q : (sel == 1) ? k2 : v;
    // Pre-scale q by (1/8)*log2e: q feeds only QK^T; scale commutes with RoPE.
    const float qs = (sel == 0) ? 0.18033688011112042f : 1.0f;
    #pragma unroll
    for (int u = 0; u < 4; ++u) {
        int coll = wc * 64 + u * 16 + l16;
        float bb = bias[n0 + coll];
        #pragma unroll
        for (int t = 0; t < 4; ++t)
            #pragma unroll
            for (int rr = 0; rr < 4; ++rr) {
                int row = R0 + wr * 64 + t * 16 + g * 4 + rr;
                outp[(size_t)row * 1024 + n0 + coll] = f2bf((acc[t][u][rr] + bb) * qs);
            }
    }
}

__global__ __launch_bounds__(256) void gemm_out_k(
    const unsigned short* __restrict__ ao, const unsigned short* __restrict__ wo,
    const float* __restrict__ bo, float* __restrict__ out)
{
    const int gn = blockIdx.y * 128;
    GEMM_BODY(ao, wo, 1024)

    #pragma unroll
    for (int u = 0; u < 4; ++u) {
        int coll = wc * 64 + u * 16 + l16;
        float bb = bo[gn + coll];
        #pragma unroll
        for (int t = 0; t < 4; ++t)
            #pragma unroll
            for (int rr = 0; rr < 4; ++rr) {
                int row = R0 + wr * 64 + t * 16 + g * 4 + rr;
                out[(size_t)row * 1024 + gn + coll] = acc[t][u][rr] + bb;
            }
    }
}

// ---------------- RoPE + fragment materialization for q and k --------------------
__global__ __launch_bounds__(256) void rope_frag_k(
    const unsigned short* __restrict__ qin, const unsigned short* __restrict__ kin,
    unsigned short* __restrict__ qfrag, unsigned short* __restrict__ kfrag)
{
    __shared__ unsigned short Ld[2][64][72];
    const int kt = blockIdx.x;        // 0..31
    const int hp = blockIdx.y;        // 0..7
    const int zz = blockIdx.z;        // bit0 = bz, bit1 = sel
    const int bz = zz & 1, sel = zz >> 1;
    const unsigned short* src = sel ? kin : qin;
    unsigned short* dstf = sel ? kfrag : qfrag;

    const int t   = threadIdx.x;
    const int r   = t & 63;
    const int c16 = (t >> 6) << 4;    // 0,16,32,48
    const int pos = kt * 64 + r;
    const size_t rowb = (size_t)(bz * Ss + pos) * 1024;

    ushort8 A0 = *(const ushort8*)&src[rowb + hp * 64 + c16];
    ushort8 A1 = *(const ushort8*)&src[rowb + hp * 64 + c16 + 8];
    ushort8 B0 = *(const ushort8*)&src[rowb + (hp + 8) * 64 + c16];
    ushort8 B1 = *(const ushort8*)&src[rowb + (hp + 8) * 64 + c16 + 8];

    #pragma unroll
    for (int i = 0; i < 16; ++i) {
        int d = c16 + i;
        float jj  = (float)(hp * 64 + d);
        float inv = exp2f(jj * -0.0259525632621414f);   // 10000^(-j/512)
        float ang = (float)pos * inv;
        float sn, cs;
        __sincosf(ang, &sn, &cs);
        unsigned short ua = (i < 8) ? A0[i] : A1[i - 8];
        unsigned short ub = (i < 8) ? B0[i] : B1[i - 8];
        float a = bf2f(ua), b = bf2f(ub);
        Ld[0][r][d] = f2bf(a * cs - b * sn);   // head hp   (low half j)
        Ld[1][r][d] = f2bf(b * cs + a * sn);   // head hp+8 (high half j+512)
    }
    __syncthreads();

    #pragma unroll
    for (int cc = 0; cc < 4; ++cc) {
        int c    = t * 4 + cc;            // 0..1023
        int hh   = c >> 9;                // head select
        int ci   = c & 511;               // chunk within head tile (0..511)
        int blk  = ci >> 7, s2 = (ci >> 6) & 1, lane2 = ci & 63;
        int gg = lane2 >> 4, ll = lane2 & 15;
        ushort8 o = *(const ushort8*)&Ld[hh][blk * 16 + ll][s2 * 32 + gg * 8];
        size_t base = (size_t)(bz * 16 + hp + hh * 8) * 131072 + (size_t)kt * 4096;
        *(ushort8*)&dstf[base + (size_t)ci * 8] = o;
    }
}

// ---------------- V fragment materialization (B-operand / V^T order) -------------
__global__ __launch_bounds__(256) void fragify_v_k(
    const unsigned short* __restrict__ v, unsigned short* __restrict__ vfrag)
{
    __shared__ unsigned short Ld[64][72];
    const int kt = blockIdx.x, bh = blockIdx.y;   // bh = bz*16+h
    const int bz = bh >> 4, h = bh & 15;
    const int t = threadIdx.x;
    const int r = t & 63, c0 = (t >> 6) << 4;
    const unsigned short* srcp = &v[(size_t)(bz * Ss + kt * 64 + r) * 1024 + h * 64 + c0];
    *(ushort8*)&Ld[r][c0]     = *(const ushort8*)srcp;
    *(ushort8*)&Ld[r][c0 + 8] = *(const ushort8*)(srcp + 8);
    __syncthreads();

    #pragma unroll
    for (int cc = 0; cc < 2; ++cc) {
        int c = t * 2 + cc;               // 0..511
        int dt4 = c >> 7, ks = (c >> 6) & 1, lane2 = c & 63;
        int gg = lane2 >> 4, ll = lane2 & 15;
        ushort8 o;
        #pragma unroll
        for (int e = 0; e < 8; ++e)
            o[e] = Ld[ks * 32 + gg * 8 + e][dt4 * 16 + ll];
        *(ushort8*)&vfrag[(size_t)bh * 131072 + (size_t)kt * 4096 + (size_t)c * 8] = o;
    }
}

// ---------------- Flash attention: all-register, split-K halves ------------------
#define FLASH_ITER(KC, KN, KT)                                                     \
    {                                                                              \
        const int ktn = kt0 + ((((KT) - kt0) + 1) & 15);                           \
        _Pragma("unroll")                                                          \
        for (int i = 0; i < 8; ++i)                                                \
            KN[i] = *(const short8*)&kfb[(size_t)ktn * 4096 + i * 512 + lane * 8]; \
        _Pragma("unroll")                                                          \
        for (int i = 0; i < 8; ++i)                                                \
            VV[i] = *(const short8*)&vfb[(size_t)(KT) * 4096 + i * 512 + lane * 8];\
        int mk[4][4];                                                              \
        _Pragma("unroll")                                                          \
        for (int k4 = 0; k4 < 4; ++k4)                                             \
            *(int4*)&mk[k4][0] =                                                   \
                *(const int4*)&mask[bz * Ss + (KT) * 64 + k4 * 16 + g * 4];        \
        f32x4 S[2][4];                                                             \
        _Pragma("unroll")                                                          \
        for (int t = 0; t < 2; ++t)                                                \
            _Pragma("unroll")                                                      \
            for (int k4 = 0; k4 < 4; ++k4) S[t][k4] = (f32x4)0.f;                  \
        __builtin_amdgcn_s_setprio(1);                                             \
        _Pragma("unroll")                                                          \
        for (int k4 = 0; k4 < 4; ++k4)                                             \
            _Pragma("unroll")                                                      \
            for (int t = 0; t < 2; ++t) {                                          \
                S[t][k4] = __builtin_amdgcn_mfma_f32_16x16x32_bf16(                \
                    KC[k4 * 2 + 0], qf[t][0], S[t][k4], 0, 0, 0);                  \
                S[t][k4] = __builtin_amdgcn_mfma_f32_16x16x32_bf16(                \
                    KC[k4 * 2 + 1], qf[t][1], S[t][k4], 0, 0, 0);                  \
            }                                                                      \
        __builtin_amdgcn_s_setprio(0);                                             \
        _Pragma("unroll")                                                          \
        for (int t = 0; t < 2; ++t)                                                \
            _Pragma("unroll")                                                      \
            for (int k4 = 0; k4 < 4; ++k4)                                         \
                _Pragma("unroll")                                                  \
                for (int r = 0; r < 4; ++r)                                        \
                    S[t][k4][r] = mk[k4][r] ? S[t][k4][r] : -1e30f;                \
        float rm[2];                                                               \
        _Pragma("unroll")                                                          \
        for (int t = 0; t < 2; ++t) {                                              \
            float m0 = fmaxf(fmaxf(S[t][0][0], S[t][0][1]), fmaxf(S[t][0][2], S[t][0][3])); \
            float m1 = fmaxf(fmaxf(S[t][1][0], S[t][1][1]), fmaxf(S[t][1][2], S[t][1][3])); \
            float m2 = fmaxf(fmaxf(S[t][2][0], S[t][2][1]), fmaxf(S[t][2][2], S[t][2][3])); \
            float m3 = fmaxf(fmaxf(S[t][3][0], S[t][3][1]), fmaxf(S[t][3][2], S[t][3][3])); \
            float m  = fmaxf(fmaxf(m0, m1), fmaxf(m2, m3));                        \
            m = fmaxf(m, __shfl_xor(m, 16));                                       \
            m = fmaxf(m, __shfl_xor(m, 32));                                       \
            rm[t] = m;                                                             \
        }                                                                          \
        bool grow = (rm[0] > mrow[0] + 10.0f) || (rm[1] > mrow[1] + 10.0f);        \
        if (__any((int)grow)) {                                                    \
            float mn0 = fmaxf(mrow[0], rm[0]);                                     \
            float mn1 = fmaxf(mrow[1], rm[1]);                                     \
            float rs0 = exp2f(mrow[0] - mn0);                                      \
            float rs1 = exp2f(mrow[1] - mn1);                                      \
            mrow[0] = mn0; mrow[1] = mn1;                                          \
            _Pragma("unroll")                                                      \
            for (int r = 0; r < 4; ++r) {                                          \
                float f0 = __shfl(rs0, g * 4 + r);                                 \
                float f1 = __shfl(rs1, g * 4 + r);                                 \
                _Pragma("unroll")                                                  \
                for (int dt = 0; dt < 4; ++dt) { O[0][dt][r] *= f0; O[1][dt][r] *= f1; } \
                Osum[0][r] *= f0; Osum[1][r] *= f1;                                \
            }                                                                      \
        }                                                                          \
        _Pragma("unroll")                                                          \
        for (int t = 0; t < 2; ++t) {                                              \
            unsigned int U[4][2];                                                  \
            _Pragma("unroll")                                                      \
            for (int k4 = 0; k4 < 4; ++k4) {                                       \
                float p0 = exp2f(S[t][k4][0] - mrow[t]);                           \
                float p1 = exp2f(S[t][k4][1] - mrow[t]);                           \
                float p2 = exp2f(S[t][k4][2] - mrow[t]);                           \
                float p3 = exp2f(S[t][k4][3] - mrow[t]);                           \
                asm("v_cvt_pk_bf16_f32 %0, %1, %2" : "=v"(U[k4][0]) : "v"(p0), "v"(p1)); \
                asm("v_cvt_pk_bf16_f32 %0, %1, %2" : "=v"(U[k4][1]) : "v"(p2), "v"(p3)); \
            }                                                                      \
            asm("v_permlane32_swap_b32 %0, %1" : "+v"(U[0][0]), "+v"(U[1][0]));    \
            asm("v_permlane32_swap_b32 %0, %1" : "+v"(U[0][1]), "+v"(U[1][1]));    \
            asm("v_permlane32_swap_b32 %0, %1" : "+v"(U[2][0]), "+v"(U[3][0]));    \
            asm("v_permlane32_swap_b32 %0, %1" : "+v"(U[2][1]), "+v"(U[3][1]));    \
            asm("v_permlane16_swap_b32 %0, %1" : "+v"(U[0][0]), "+v"(U[1][0]));    \
            asm("v_permlane16_swap_b32 %0, %1" : "+v"(U[0][1]), "+v"(U[1][1]));    \
            asm("v_permlane16_swap_b32 %0, %1" : "+v"(U[2][0]), "+v"(U[3][0]));    \
            asm("v_permlane16_swap_b32 %0, %1" : "+v"(U[2][1]), "+v"(U[3][1]));    \
            __builtin_amdgcn_s_setprio(1);                                         \
            _Pragma("unroll")                                                      \
            for (int ks = 0; ks < 2; ++ks) {                                       \
                u32x4 gp;                                                          \
                gp[0] = U[2 * ks][0]; gp[1] = U[2 * ks][1];                        \
                gp[2] = U[2 * ks + 1][0]; gp[3] = U[2 * ks + 1][1];                \
                short8 pf = __builtin_bit_cast(short8, gp);                        \
                Osum[t] = __builtin_amdgcn_mfma_f32_16x16x32_bf16(pf, ones, Osum[t], 0, 0, 0); \
                _Pragma("unroll")                                                  \
                for (int dt = 0; dt < 4; ++dt)                                     \
                    O[t][dt] = __builtin_amdgcn_mfma_f32_16x16x32_bf16(            \
                        pf, VV[dt * 2 + ks], O[t][dt], 0, 0, 0);                   \
            }                                                                      \
            __builtin_amdgcn_s_setprio(0);                                         \
        }                                                                          \
    }

__global__ __launch_bounds__(256) void flash_k(
    const unsigned short* __restrict__ qfrag, const unsigned short* __restrict__ kfrag,
    const unsigned short* __restrict__ vfrag, const int* __restrict__ mask,
    unsigned short* __restrict__ opart, float2* __restrict__ ml)
{
    // Bijective XCD remap: 1024 blocks = 8 XCDs x (4 (h,bz) groups x 16 qb x 2 half).
    const int F   = blockIdx.x;
    const int xcd = F & 7, j = F >> 3;          // j: 0..127
    const int grp = xcd * 4 + (j >> 5);         // 0..31
    const int rem = j & 31;
    const int qb  = rem >> 1;
    const int half = rem & 1;
    const int h   = grp & 15;
    const int bz  = grp >> 4;
    const int kt0 = half * 16;

    const int tid  = threadIdx.x;
    const int lane = tid & 63;
    const int w    = tid >> 6;
    const int l16  = lane & 15;
    const int g    = lane >> 4;

    const size_t fb = (size_t)(bz * 16 + h) * 131072;
    const unsigned short* kfb = kfrag + fb;
    const unsigned short* vfb = vfrag + fb;
    const unsigned short* qfb = qfrag + fb;

    // Q fragments (pre-scaled): blk16 = qb*8 + w*2 + t
    short8 qf[2][2];
    #pragma unroll
    for (int t = 0; t < 2; ++t)
        #pragma unroll
        for (int s = 0; s < 2; ++s)
            qf[t][s] = *(const short8*)&qfb[(size_t)(qb * 8 + w * 2 + t) * 1024
                                            + s * 512 + lane * 8];

    f32x4 O[2][4];
    #pragma unroll
    for (int t = 0; t < 2; ++t)
        #pragma unroll
        for (int d = 0; d < 4; ++d) O[t][d] = (f32x4)0.f;
    f32x4 Osum[2];
    Osum[0] = (f32x4)0.f; Osum[1] = (f32x4)0.f;
    float mrow[2] = {-1.0e4f, -1.0e4f};

    short8 ones;
    #pragma unroll
    for (int e = 0; e < 8; ++e) ones[e] = (short)0x3F80;  // bf16 1.0

    short8 KA[8], KB[8], VV[8];
    #pragma unroll
    for (int i = 0; i < 8; ++i)
        KA[i] = *(const short8*)&kfb[(size_t)kt0 * 4096 + i * 512 + lane * 8];

    for (int kt2 = 0; kt2 < 16; kt2 += 2) {
        FLASH_ITER(KA, KB, kt0 + kt2)
        FLASH_ITER(KB, KA, kt0 + kt2 + 1)
    }

    // ---- epilogue: normalized partial O (bf16) + per-query (m, sum) ----
    const size_t NE = (size_t)Mm * Hh;
    #pragma unroll
    for (int t = 0; t < 2; ++t)
        #pragma unroll
        for (int r = 0; r < 4; ++r) {
            float osum = Osum[t][r];
            float inv  = osum > 0.f ? 1.0f / osum : 0.f;
            float mo   = __shfl(mrow[t], g * 4 + r);   // S-layout m -> O-layout
            int rowl   = qb * 128 + w * 32 + t * 16 + g * 4 + r;   // 0..2047
            size_t ob  = (size_t)half * NE
                       + ((size_t)(bz * Ss + rowl)) * 1024 + h * 64;
            #pragma unroll
            for (int dt = 0; dt < 4; ++dt)
                opart[ob + dt * 16 + l16] = f2bf(O[t][dt][r] * inv);
            if (l16 == 0)
                ml[((half * 2 + bz) * 16 + h) * 2048 + rowl] = make_float2(mo, osum);
        }
}

// ---------------- Combine split-K halves -----------------------------------------
__global__ __launch_bounds__(256) void combine_k(
    const unsigned short* __restrict__ opart, const float2* __restrict__ ml,
    unsigned short* __restrict__ ao)
{
    const size_t NE = (size_t)Mm * Hh;
    int c    = blockIdx.x * 256 + threadIdx.x;   // 0..524287 (4096 rows x 128)
    int row  = c >> 7;                           // bz*2048 + qrow
    int col8 = c & 127;
    int h    = col8 >> 3;
    int bz   = row >> 11, qrow = row & 2047;

    float2 a = ml[((0 * 2 + bz) * 16 + h) * 2048 + qrow];
    float2 b = ml[((1 * 2 + bz) * 16 + h) * 2048 + qrow];
    float M  = fmaxf(a.x, b.x);
    float w1 = exp2f(a.x - M) * a.y;
    float w2 = exp2f(b.x - M) * b.y;
    float tot = w1 + w2;
    float inv = tot > 0.f ? 1.0f / tot : 0.f;
    w1 *= inv; w2 *= inv;

    ushort8 o1 = *(const ushort8*)&opart[(size_t)c * 8];
    ushort8 o2 = *(const ushort8*)&opart[NE + (size_t)c * 8];
    ushort8 o;
    #pragma unroll
    for (int jj = 0; jj < 8; ++jj)
        o[jj] = f2bf(bf2f(o1[jj]) * w1 + bf2f(o2[jj]) * w2);
    *(ushort8*)&ao[(size_t)c * 8] = o;
}

extern "C" void kernel_launch(void* const* d_in, const int* in_sizes, int n_in,
                              void* d_out, int out_size, void* d_ws, size_t ws_size,
                              hipStream_t stream)
{
    const float* x  = (const float*)d_in[0];
    const int*   am = (const int*)d_in[1];
    const float* Wq = (const float*)d_in[2];
    const float* bq = (const float*)d_in[3];
    const float* Wk = (const float*)d_in[4];
    const float* bk = (const float*)d_in[5];
    const float* Wv = (const float*)d_in[6];
    const float* bv = (const float*)d_in[7];
    const float* Wo = (const float*)d_in[8];
    const float* bo = (const float*)d_in[9];
    float* out = (float*)d_out;

    const size_t NE = (size_t)Mm * Hh;           // 4M elems
    unsigned short* q     = (unsigned short*)d_ws;
    unsigned short* k     = q + NE;
    unsigned short* v     = k + NE;
    unsigned short* ao    = v + NE;
    unsigned short* xb    = ao + NE;             // gemm input; reused as qfrag
    unsigned short* wall  = xb + NE;             // [Wq;Wk;Wv;Wo] rows
    unsigned short* wo    = wall + 3u * 1048576u;
    unsigned short* kfrag = wall + 4u * 1048576u;
    unsigned short* qfrag = xb;                  // xb dead after gemm_qkv
    unsigned short* vfrag = q;                   // q dead after rope_frag
    unsigned short* opart = k;                   // k,v dead once frags built (16 MB)
    float2*         ml    = (float2*)(kfrag + 4u * 1048576u);   // +1 MB

    convert_k<<<(2 * NE) / (256 * 8), 256, 0, stream>>>(x, Wq, Wk, Wv, Wo, xb, wall);
    gemm_qkv_k<<<dim3(Mm / 128, 3072 / 128), 256, 0, stream>>>(
        xb, wall, bq, bk, bv, q, k, v);
    rope_frag_k<<<dim3(32, 8, 4), 256, 0, stream>>>(q, k, qfrag, kfrag);
    fragify_v_k<<<dim3(32, 32), 256, 0, stream>>>(v, vfrag);
    flash_k<<<dim3(1024), 256, 0, stream>>>(qfrag, kfrag, vfrag, am, opart, ml);
    combine_k<<<dim3((Mm * 128) / 256), 256, 0, stream>>>(opart, ml, ao);
    gemm_out_k<<<dim3(Mm / 128, Hh / 128), 256, 0, stream>>>(ao, wo, bo, out);
}

// Round 13
// 187.091 us; speedup vs baseline: 2.5876x; 1.0886x over previous
//
#include <hip/hip_runtime.h>
#include <hip/hip_bf16.h>

// GQA forward, round 12: split-K all-register flash with the round-9 iteration
// body verbatim (NO s_setprio — it fenced the scheduler, extended K/V live
// ranges, VGPR 84->136, occupancy 11%). Split-K bounds + partial epilogue +
// combine kept (verified correct in rounds 10-11).
// B=2, S=2048, HIDDEN=1024, 16 heads x 64 dim, RoPE over full hidden (half=512).
// ws (ushort elems): q k v ao xb wall kfrag (7 x 4M = 56 MB) + ml (1 MB).

constexpr int Bb  = 2;
constexpr int Ss  = 2048;
constexpr int Hh  = 1024;
constexpr int NHh = 16;
constexpr int Mm  = Bb * Ss;   // 4096 rows

typedef __attribute__((ext_vector_type(8))) unsigned short ushort8;
typedef __attribute__((ext_vector_type(8))) short short8;
typedef __attribute__((ext_vector_type(4))) float f32x4;
typedef __attribute__((ext_vector_type(4))) unsigned int u32x4;

__device__ __forceinline__ unsigned short f2bf(float f) {
    unsigned int u = __float_as_uint(f);
    u += 0x7fffu + ((u >> 16) & 1u);
    return (unsigned short)(u >> 16);
}
__device__ __forceinline__ float bf2f(unsigned short h) {
    return __uint_as_float(((unsigned int)h) << 16);
}
__device__ __forceinline__ void gload16(const void* g, void* l) {
    __builtin_amdgcn_global_load_lds(
        (const __attribute__((address_space(1))) unsigned int*)g,
        (__attribute__((address_space(3))) unsigned int*)l, 16, 0, 0);
}

// ---------------- fp32 -> bf16 convert (x, Wq|Wk|Wv|Wo into one block) ----------
__global__ __launch_bounds__(256) void convert_k(
    const float* __restrict__ x,
    const float* __restrict__ Wq, const float* __restrict__ Wk,
    const float* __restrict__ Wv, const float* __restrict__ Wo,
    unsigned short* __restrict__ xb, unsigned short* __restrict__ wall)
{
    size_t e = ((size_t)blockIdx.x * 256 + threadIdx.x) << 3;
    const float* s; unsigned short* d;
    if (e < (size_t)Mm * Hh) {
        s = x + e; d = xb + e;
    } else {
        size_t f = e - (size_t)Mm * Hh;
        int t = (int)(f >> 20);
        const float* w = (t == 0) ? Wq : (t == 1) ? Wk : (t == 2) ? Wv : Wo;
        s = w + (f & 1048575);
        d = wall + f;
    }
    float4 a = *(const float4*)s;
    float4 b = *(const float4*)(s + 4);
    ushort8 o;
    o[0] = f2bf(a.x); o[1] = f2bf(a.y); o[2] = f2bf(a.z); o[3] = f2bf(a.w);
    o[4] = f2bf(b.x); o[5] = f2bf(b.y); o[6] = f2bf(b.z); o[7] = f2bf(b.w);
    *(ushort8*)d = o;
}

// ---------------- bf16 MFMA GEMM core (unchanged) --------------------------------
#define GEMM_BODY(ATYPE_PTR, WPTR, K0MAX)                                          \
    __shared__ unsigned short As[128 * 64];                                        \
    __shared__ unsigned short Bs[128 * 64];                                        \
    const int tid  = threadIdx.x;                                                  \
    const int lane = tid & 63;                                                     \
    const int w    = tid >> 6;                                                     \
    const int wr   = w >> 1, wc = w & 1;                                           \
    const int l16  = lane & 15, g = lane >> 4;                                     \
    const int R0   = blockIdx.x * 128;                                             \
    char* asb = (char*)As; char* bsb = (char*)Bs;                                  \
    f32x4 acc[4][4] = {};                                                          \
    for (int k0 = 0; k0 < K0MAX; k0 += 64) {                                       \
        _Pragma("unroll")                                                          \
        for (int it = 0; it < 4; ++it) {                                           \
            int sbase = w * 4096 + it * 1024;                                      \
            int boff  = sbase + lane * 16;                                         \
            int r     = boff >> 7;                                                 \
            int c     = (boff >> 4) & 7;                                           \
            int col   = k0 + ((c ^ (r & 7)) << 3);                                 \
            gload16(&ATYPE_PTR[(size_t)(R0 + r) * 1024 + col], asb + sbase);       \
            gload16(&WPTR[(size_t)(gn + r) * 1024 + col], bsb + sbase);            \
        }                                                                          \
        __syncthreads();                                                           \
        short8 bfrag[4][2];                                                        \
        _Pragma("unroll")                                                          \
        for (int u = 0; u < 4; ++u) {                                              \
            int row = wc * 64 + u * 16 + l16;                                      \
            _Pragma("unroll")                                                      \
            for (int s = 0; s < 2; ++s)                                            \
                bfrag[u][s] = *(const short8*)(bsb + row * 128 +                   \
                               ((s * 64 + g * 16) ^ ((row & 7) << 4)));            \
        }                                                                          \
        _Pragma("unroll")                                                          \
        for (int t = 0; t < 4; ++t) {                                              \
            int row = wr * 64 + t * 16 + l16;                                      \
            short8 af[2];                                                          \
            _Pragma("unroll")                                                      \
            for (int s = 0; s < 2; ++s)                                            \
                af[s] = *(const short8*)(asb + row * 128 +                         \
                         ((s * 64 + g * 16) ^ ((row & 7) << 4)));                  \
            _Pragma("unroll")                                                      \
            for (int u = 0; u < 4; ++u) {                                          \
                acc[t][u] = __builtin_amdgcn_mfma_f32_16x16x32_bf16(af[0], bfrag[u][0], acc[t][u], 0, 0, 0); \
                acc[t][u] = __builtin_amdgcn_mfma_f32_16x16x32_bf16(af[1], bfrag[u][1], acc[t][u], 0, 0, 0); \
            }                                                                      \
        }                                                                          \
        __syncthreads();                                                           \
    }

__global__ __launch_bounds__(256) void gemm_qkv_k(
    const unsigned short* __restrict__ xb, const unsigned short* __restrict__ wall,
    const float* __restrict__ bq, const float* __restrict__ bk, const float* __restrict__ bv,
    unsigned short* __restrict__ q, unsigned short* __restrict__ k2,
    unsigned short* __restrict__ v)
{
    const int gn = blockIdx.y * 128;
    GEMM_BODY(xb, wall, 1024)

    const int sel = gn >> 10;
    const int n0  = gn & 1023;
    const float* bias = (sel == 0) ? bq : (sel == 1) ? bk : bv;
    unsigned short* outp = (sel == 0) ? q : (sel == 1) ? k2 : v;
    // Pre-scale q by (1/8)*log2e: q feeds only QK^T; scale commutes with RoPE.
    const float qs = (sel == 0) ? 0.18033688011112042f : 1.0f;
    #pragma unroll
    for (int u = 0; u < 4; ++u) {
        int coll = wc * 64 + u * 16 + l16;
        float bb = bias[n0 + coll];
        #pragma unroll
        for (int t = 0; t < 4; ++t)
            #pragma unroll
            for (int rr = 0; rr < 4; ++rr) {
                int row = R0 + wr * 64 + t * 16 + g * 4 + rr;
                outp[(size_t)row * 1024 + n0 + coll] = f2bf((acc[t][u][rr] + bb) * qs);
            }
    }
}

__global__ __launch_bounds__(256) void gemm_out_k(
    const unsigned short* __restrict__ ao, const unsigned short* __restrict__ wo,
    const float* __restrict__ bo, float* __restrict__ out)
{
    const int gn = blockIdx.y * 128;
    GEMM_BODY(ao, wo, 1024)

    #pragma unroll
    for (int u = 0; u < 4; ++u) {
        int coll = wc * 64 + u * 16 + l16;
        float bb = bo[gn + coll];
        #pragma unroll
        for (int t = 0; t < 4; ++t)
            #pragma unroll
            for (int rr = 0; rr < 4; ++rr) {
                int row = R0 + wr * 64 + t * 16 + g * 4 + rr;
                out[(size_t)row * 1024 + gn + coll] = acc[t][u][rr] + bb;
            }
    }
}

// ---------------- RoPE + fragment materialization for q and k --------------------
__global__ __launch_bounds__(256) void rope_frag_k(
    const unsigned short* __restrict__ qin, const unsigned short* __restrict__ kin,
    unsigned short* __restrict__ qfrag, unsigned short* __restrict__ kfrag)
{
    __shared__ unsigned short Ld[2][64][72];
    const int kt = blockIdx.x;        // 0..31
    const int hp = blockIdx.y;        // 0..7
    const int zz = blockIdx.z;        // bit0 = bz, bit1 = sel
    const int bz = zz & 1, sel = zz >> 1;
    const unsigned short* src = sel ? kin : qin;
    unsigned short* dstf = sel ? kfrag : qfrag;

    const int t   = threadIdx.x;
    const int r   = t & 63;
    const int c16 = (t >> 6) << 4;    // 0,16,32,48
    const int pos = kt * 64 + r;
    const size_t rowb = (size_t)(bz * Ss + pos) * 1024;

    ushort8 A0 = *(const ushort8*)&src[rowb + hp * 64 + c16];
    ushort8 A1 = *(const ushort8*)&src[rowb + hp * 64 + c16 + 8];
    ushort8 B0 = *(const ushort8*)&src[rowb + (hp + 8) * 64 + c16];
    ushort8 B1 = *(const ushort8*)&src[rowb + (hp + 8) * 64 + c16 + 8];

    #pragma unroll
    for (int i = 0; i < 16; ++i) {
        int d = c16 + i;
        float jj  = (float)(hp * 64 + d);
        float inv = exp2f(jj * -0.0259525632621414f);   // 10000^(-j/512)
        float ang = (float)pos * inv;
        float sn, cs;
        __sincosf(ang, &sn, &cs);
        unsigned short ua = (i < 8) ? A0[i] : A1[i - 8];
        unsigned short ub = (i < 8) ? B0[i] : B1[i - 8];
        float a = bf2f(ua), b = bf2f(ub);
        Ld[0][r][d] = f2bf(a * cs - b * sn);   // head hp   (low half j)
        Ld[1][r][d] = f2bf(b * cs + a * sn);   // head hp+8 (high half j+512)
    }
    __syncthreads();

    #pragma unroll
    for (int cc = 0; cc < 4; ++cc) {
        int c    = t * 4 + cc;            // 0..1023
        int hh   = c >> 9;                // head select
        int ci   = c & 511;               // chunk within head tile (0..511)
        int blk  = ci >> 7, s2 = (ci >> 6) & 1, lane2 = ci & 63;
        int gg = lane2 >> 4, ll = lane2 & 15;
        ushort8 o = *(const ushort8*)&Ld[hh][blk * 16 + ll][s2 * 32 + gg * 8];
        size_t base = (size_t)(bz * 16 + hp + hh * 8) * 131072 + (size_t)kt * 4096;
        *(ushort8*)&dstf[base + (size_t)ci * 8] = o;
    }
}

// ---------------- V fragment materialization (B-operand / V^T order) -------------
__global__ __launch_bounds__(256) void fragify_v_k(
    const unsigned short* __restrict__ v, unsigned short* __restrict__ vfrag)
{
    __shared__ unsigned short Ld[64][72];
    const int kt = blockIdx.x, bh = blockIdx.y;   // bh = bz*16+h
    const int bz = bh >> 4, h = bh & 15;
    const int t = threadIdx.x;
    const int r = t & 63, c0 = (t >> 6) << 4;
    const unsigned short* srcp = &v[(size_t)(bz * Ss + kt * 64 + r) * 1024 + h * 64 + c0];
    *(ushort8*)&Ld[r][c0]     = *(const ushort8*)srcp;
    *(ushort8*)&Ld[r][c0 + 8] = *(const ushort8*)(srcp + 8);
    __syncthreads();

    #pragma unroll
    for (int cc = 0; cc < 2; ++cc) {
        int c = t * 2 + cc;               // 0..511
        int dt4 = c >> 7, ks = (c >> 6) & 1, lane2 = c & 63;
        int gg = lane2 >> 4, ll = lane2 & 15;
        ushort8 o;
        #pragma unroll
        for (int e = 0; e < 8; ++e)
            o[e] = Ld[ks * 32 + gg * 8 + e][dt4 * 16 + ll];
        *(ushort8*)&vfrag[(size_t)bh * 131072 + (size_t)kt * 4096 + (size_t)c * 8] = o;
    }
}

// ---------------- Flash attention: all-register, split-K, round-9 body -----------
#define FLASH_ITER(KC, KN, KT)                                                     \
    {                                                                              \
        const int ktn = kt0 + ((((KT) - kt0) + 1) & 15);                           \
        _Pragma("unroll")                                                          \
        for (int i = 0; i < 8; ++i)                                                \
            KN[i] = *(const short8*)&kfb[(size_t)ktn * 4096 + i * 512 + lane * 8]; \
        _Pragma("unroll")                                                          \
        for (int i = 0; i < 8; ++i)                                                \
            VV[i] = *(const short8*)&vfb[(size_t)(KT) * 4096 + i * 512 + lane * 8];\
        int mk[4][4];                                                              \
        _Pragma("unroll")                                                          \
        for (int k4 = 0; k4 < 4; ++k4)                                             \
            *(int4*)&mk[k4][0] =                                                   \
                *(const int4*)&mask[bz * Ss + (KT) * 64 + k4 * 16 + g * 4];        \
        f32x4 S[2][4];                                                             \
        _Pragma("unroll")                                                          \
        for (int t = 0; t < 2; ++t)                                                \
            _Pragma("unroll")                                                      \
            for (int k4 = 0; k4 < 4; ++k4) S[t][k4] = (f32x4)0.f;                  \
        _Pragma("unroll")                                                          \
        for (int k4 = 0; k4 < 4; ++k4)                                             \
            _Pragma("unroll")                                                      \
            for (int t = 0; t < 2; ++t) {                                          \
                S[t][k4] = __builtin_amdgcn_mfma_f32_16x16x32_bf16(                \
                    KC[k4 * 2 + 0], qf[t][0], S[t][k4], 0, 0, 0);                  \
                S[t][k4] = __builtin_amdgcn_mfma_f32_16x16x32_bf16(                \
                    KC[k4 * 2 + 1], qf[t][1], S[t][k4], 0, 0, 0);                  \
            }                                                                      \
        _Pragma("unroll")                                                          \
        for (int t = 0; t < 2; ++t)                                                \
            _Pragma("unroll")                                                      \
            for (int k4 = 0; k4 < 4; ++k4)                                         \
                _Pragma("unroll")                                                  \
                for (int r = 0; r < 4; ++r)                                        \
                    S[t][k4][r] = mk[k4][r] ? S[t][k4][r] : -1e30f;                \
        float rm[2];                                                               \
        _Pragma("unroll")                                                          \
        for (int t = 0; t < 2; ++t) {                                              \
            float m0 = fmaxf(fmaxf(S[t][0][0], S[t][0][1]), fmaxf(S[t][0][2], S[t][0][3])); \
            float m1 = fmaxf(fmaxf(S[t][1][0], S[t][1][1]), fmaxf(S[t][1][2], S[t][1][3])); \
            float m2 = fmaxf(fmaxf(S[t][2][0], S[t][2][1]), fmaxf(S[t][2][2], S[t][2][3])); \
            float m3 = fmaxf(fmaxf(S[t][3][0], S[t][3][1]), fmaxf(S[t][3][2], S[t][3][3])); \
            float m  = fmaxf(fmaxf(m0, m1), fmaxf(m2, m3));                        \
            m = fmaxf(m, __shfl_xor(m, 16));                                       \
            m = fmaxf(m, __shfl_xor(m, 32));                                       \
            rm[t] = m;                                                             \
        }                                                                          \
        bool grow = (rm[0] > mrow[0] + 10.0f) || (rm[1] > mrow[1] + 10.0f);        \
        if (__any((int)grow)) {                                                    \
            float mn0 = fmaxf(mrow[0], rm[0]);                                     \
            float mn1 = fmaxf(mrow[1], rm[1]);                                     \
            float rs0 = exp2f(mrow[0] - mn0);                                      \
            float rs1 = exp2f(mrow[1] - mn1);                                      \
            mrow[0] = mn0; mrow[1] = mn1;                                          \
            _Pragma("unroll")                                                      \
            for (int r = 0; r < 4; ++r) {                                          \
                float f0 = __shfl(rs0, g * 4 + r);                                 \
                float f1 = __shfl(rs1, g * 4 + r);                                 \
                _Pragma("unroll")                                                  \
                for (int dt = 0; dt < 4; ++dt) { O[0][dt][r] *= f0; O[1][dt][r] *= f1; } \
                Osum[0][r] *= f0; Osum[1][r] *= f1;                                \
            }                                                                      \
        }                                                                          \
        _Pragma("unroll")                                                          \
        for (int t = 0; t < 2; ++t) {                                              \
            unsigned int U[4][2];                                                  \
            _Pragma("unroll")                                                      \
            for (int k4 = 0; k4 < 4; ++k4) {                                       \
                float p0 = exp2f(S[t][k4][0] - mrow[t]);                           \
                float p1 = exp2f(S[t][k4][1] - mrow[t]);                           \
                float p2 = exp2f(S[t][k4][2] - mrow[t]);                           \
                float p3 = exp2f(S[t][k4][3] - mrow[t]);                           \
                asm("v_cvt_pk_bf16_f32 %0, %1, %2" : "=v"(U[k4][0]) : "v"(p0), "v"(p1)); \
                asm("v_cvt_pk_bf16_f32 %0, %1, %2" : "=v"(U[k4][1]) : "v"(p2), "v"(p3)); \
            }                                                                      \
            asm("v_permlane32_swap_b32 %0, %1" : "+v"(U[0][0]), "+v"(U[1][0]));    \
            asm("v_permlane32_swap_b32 %0, %1" : "+v"(U[0][1]), "+v"(U[1][1]));    \
            asm("v_permlane32_swap_b32 %0, %1" : "+v"(U[2][0]), "+v"(U[3][0]));    \
            asm("v_permlane32_swap_b32 %0, %1" : "+v"(U[2][1]), "+v"(U[3][1]));    \
            asm("v_permlane16_swap_b32 %0, %1" : "+v"(U[0][0]), "+v"(U[1][0]));    \
            asm("v_permlane16_swap_b32 %0, %1" : "+v"(U[0][1]), "+v"(U[1][1]));    \
            asm("v_permlane16_swap_b32 %0, %1" : "+v"(U[2][0]), "+v"(U[3][0]));    \
            asm("v_permlane16_swap_b32 %0, %1" : "+v"(U[2][1]), "+v"(U[3][1]));    \
            _Pragma("unroll")                                                      \
            for (int ks = 0; ks < 2; ++ks) {                                       \
                u32x4 gp;                                                          \
                gp[0] = U[2 * ks][0]; gp[1] = U[2 * ks][1];                        \
                gp[2] = U[2 * ks + 1][0]; gp[3] = U[2 * ks + 1][1];                \
                short8 pf = __builtin_bit_cast(short8, gp);                        \
                Osum[t] = __builtin_amdgcn_mfma_f32_16x16x32_bf16(pf, ones, Osum[t], 0, 0, 0); \
                _Pragma("unroll")                                                  \
                for (int dt = 0; dt < 4; ++dt)                                     \
                    O[t][dt] = __builtin_amdgcn_mfma_f32_16x16x32_bf16(            \
                        pf, VV[dt * 2 + ks], O[t][dt], 0, 0, 0);                   \
            }                                                                      \
        }                                                                          \
    }

__global__ __launch_bounds__(256) void flash_k(
    const unsigned short* __restrict__ qfrag, const unsigned short* __restrict__ kfrag,
    const unsigned short* __restrict__ vfrag, const int* __restrict__ mask,
    unsigned short* __restrict__ opart, float2* __restrict__ ml)
{
    // Bijective XCD remap: 1024 blocks = 8 XCDs x (4 (h,bz) groups x 16 qb x 2 half).
    const int F   = blockIdx.x;
    const int xcd = F & 7, j = F >> 3;          // j: 0..127
    const int grp = xcd * 4 + (j >> 5);         // 0..31
    const int rem = j & 31;
    const int qb  = rem >> 1;
    const int half = rem & 1;
    const int h   = grp & 15;
    const int bz  = grp >> 4;
    const int kt0 = half * 16;

    const int tid  = threadIdx.x;
    const int lane = tid & 63;
    const int w    = tid >> 6;
    const int l16  = lane & 15;
    const int g    = lane >> 4;

    const size_t fb = (size_t)(bz * 16 + h) * 131072;
    const unsigned short* kfb = kfrag + fb;
    const unsigned short* vfb = vfrag + fb;
    const unsigned short* qfb = qfrag + fb;

    // Q fragments (pre-scaled): blk16 = qb*8 + w*2 + t
    short8 qf[2][2];
    #pragma unroll
    for (int t = 0; t < 2; ++t)
        #pragma unroll
        for (int s = 0; s < 2; ++s)
            qf[t][s] = *(const short8*)&qfb[(size_t)(qb * 8 + w * 2 + t) * 1024
                                            + s * 512 + lane * 8];

    f32x4 O[2][4];
    #pragma unroll
    for (int t = 0; t < 2; ++t)
        #pragma unroll
        for (int d = 0; d < 4; ++d) O[t][d] = (f32x4)0.f;
    f32x4 Osum[2];
    Osum[0] = (f32x4)0.f; Osum[1] = (f32x4)0.f;
    float mrow[2] = {-1.0e4f, -1.0e4f};

    short8 ones;
    #pragma unroll
    for (int e = 0; e < 8; ++e) ones[e] = (short)0x3F80;  // bf16 1.0

    short8 KA[8], KB[8], VV[8];
    #pragma unroll
    for (int i = 0; i < 8; ++i)
        KA[i] = *(const short8*)&kfb[(size_t)kt0 * 4096 + i * 512 + lane * 8];

    for (int kt2 = 0; kt2 < 16; kt2 += 2) {
        FLASH_ITER(KA, KB, kt0 + kt2)
        FLASH_ITER(KB, KA, kt0 + kt2 + 1)
    }

    // ---- epilogue: normalized partial O (bf16) + per-query (m, sum) ----
    const size_t NE = (size_t)Mm * Hh;
    #pragma unroll
    for (int t = 0; t < 2; ++t)
        #pragma unroll
        for (int r = 0; r < 4; ++r) {
            float osum = Osum[t][r];
            float inv  = osum > 0.f ? 1.0f / osum : 0.f;
            float mo   = __shfl(mrow[t], g * 4 + r);   // S-layout m -> O-layout
            int rowl   = qb * 128 + w * 32 + t * 16 + g * 4 + r;   // 0..2047
            size_t ob  = (size_t)half * NE
                       + ((size_t)(bz * Ss + rowl)) * 1024 + h * 64;
            #pragma unroll
            for (int dt = 0; dt < 4; ++dt)
                opart[ob + dt * 16 + l16] = f2bf(O[t][dt][r] * inv);
            if (l16 == 0)
                ml[((half * 2 + bz) * 16 + h) * 2048 + rowl] = make_float2(mo, osum);
        }
}

// ---------------- Combine split-K halves -----------------------------------------
__global__ __launch_bounds__(256) void combine_k(
    const unsigned short* __restrict__ opart, const float2* __restrict__ ml,
    unsigned short* __restrict__ ao)
{
    const size_t NE = (size_t)Mm * Hh;
    int c    = blockIdx.x * 256 + threadIdx.x;   // 0..524287 (4096 rows x 128)
    int row  = c >> 7;                           // bz*2048 + qrow
    int col8 = c & 127;
    int h    = col8 >> 3;
    int bz   = row >> 11, qrow = row & 2047;

    float2 a = ml[((0 * 2 + bz) * 16 + h) * 2048 + qrow];
    float2 b = ml[((1 * 2 + bz) * 16 + h) * 2048 + qrow];
    float M  = fmaxf(a.x, b.x);
    float w1 = exp2f(a.x - M) * a.y;
    float w2 = exp2f(b.x - M) * b.y;
    float tot = w1 + w2;
    float inv = tot > 0.f ? 1.0f / tot : 0.f;
    w1 *= inv; w2 *= inv;

    ushort8 o1 = *(const ushort8*)&opart[(size_t)c * 8];
    ushort8 o2 = *(const ushort8*)&opart[NE + (size_t)c * 8];
    ushort8 o;
    #pragma unroll
    for (int jj = 0; jj < 8; ++jj)
        o[jj] = f2bf(bf2f(o1[jj]) * w1 + bf2f(o2[jj]) * w2);
    *(ushort8*)&ao[(size_t)c * 8] = o;
}

extern "C" void kernel_launch(void* const* d_in, const int* in_sizes, int n_in,
                              void* d_out, int out_size, void* d_ws, size_t ws_size,
                              hipStream_t stream)
{
    const float* x  = (const float*)d_in[0];
    const int*   am = (const int*)d_in[1];
    const float* Wq = (const float*)d_in[2];
    const float* bq = (const float*)d_in[3];
    const float* Wk = (const float*)d_in[4];
    const float* bk = (const float*)d_in[5];
    const float* Wv = (const float*)d_in[6];
    const float* bv = (const float*)d_in[7];
    const float* Wo = (const float*)d_in[8];
    const float* bo = (const float*)d_in[9];
    float* out = (float*)d_out;

    const size_t NE = (size_t)Mm * Hh;           // 4M elems
    unsigned short* q     = (unsigned short*)d_ws;
    unsigned short* k     = q + NE;
    unsigned short* v     = k + NE;
    unsigned short* ao    = v + NE;
    unsigned short* xb    = ao + NE;             // gemm input; reused as qfrag
    unsigned short* wall  = xb + NE;             // [Wq;Wk;Wv;Wo] rows
    unsigned short* wo    = wall + 3u * 1048576u;
    unsigned short* kfrag = wall + 4u * 1048576u;
    unsigned short* qfrag = xb;                  // xb dead after gemm_qkv
    unsigned short* vfrag = q;                   // q dead after rope_frag
    unsigned short* opart = k;                   // k,v dead once frags built (16 MB)
    float2*         ml    = (float2*)(kfrag + 4u * 1048576u);   // +1 MB

    convert_k<<<(2 * NE) / (256 * 8), 256, 0, stream>>>(x, Wq, Wk, Wv, Wo, xb, wall);
    gemm_qkv_k<<<dim3(Mm / 128, 3072 / 128), 256, 0, stream>>>(
        xb, wall, bq, bk, bv, q, k, v);
    rope_frag_k<<<dim3(32, 8, 4), 256, 0, stream>>>(q, k, qfrag, kfrag);
    fragify_v_k<<<dim3(32, 32), 256, 0, stream>>>(v, vfrag);
    flash_k<<<dim3(1024), 256, 0, stream>>>(qfrag, kfrag, vfrag, am, opart, ml);
    combine_k<<<dim3((Mm * 128) / 256), 256, 0, stream>>>(opart, ml, ao);
    gemm_out_k<<<dim3(Mm / 128, Hh / 128), 256, 0, stream>>>(ao, wo, bo, out);
}

// Round 15
// 162.106 us; speedup vs baseline: 2.9865x; 1.1541x over previous
//
#include <hip/hip_runtime.h>
#include <hip/hip_bf16.h>

// GQA forward, round 14: round 13 with the ws overlap bug fixed — maskbf now
// sits AFTER ml's full 1 MB extent (ml max index is ((half*2+bz)*16+h)*2048+row
// = 131071; round 13 put maskbf at ml+65536, inside ml's upper half, so flash's
// ml writes clobbered maskbf mid-flight -> NaN).
// Kernel content otherwise identical to round 13: split-K all-register flash,
// __launch_bounds__(256,2), mask folded into MFMA operands (zeroed V rows +
// bf16 0/1 mask fragment for the row-sum MFMA).
// B=2, S=2048, HIDDEN=1024, 16 heads x 64 dim, RoPE over full hidden (half=512).
// ws (ushort elems): q k v ao xb wall kfrag (7 x 4M = 56 MB) + ml (1 MB) + maskbf (8 KB).

constexpr int Bb  = 2;
constexpr int Ss  = 2048;
constexpr int Hh  = 1024;
constexpr int NHh = 16;
constexpr int Mm  = Bb * Ss;   // 4096 rows

typedef __attribute__((ext_vector_type(8))) unsigned short ushort8;
typedef __attribute__((ext_vector_type(8))) short short8;
typedef __attribute__((ext_vector_type(4))) float f32x4;
typedef __attribute__((ext_vector_type(4))) unsigned int u32x4;

__device__ __forceinline__ unsigned short f2bf(float f) {
    unsigned int u = __float_as_uint(f);
    u += 0x7fffu + ((u >> 16) & 1u);
    return (unsigned short)(u >> 16);
}
__device__ __forceinline__ float bf2f(unsigned short h) {
    return __uint_as_float(((unsigned int)h) << 16);
}
__device__ __forceinline__ void gload16(const void* g, void* l) {
    __builtin_amdgcn_global_load_lds(
        (const __attribute__((address_space(1))) unsigned int*)g,
        (__attribute__((address_space(3))) unsigned int*)l, 16, 0, 0);
}

// ---------------- fp32 -> bf16 convert (x, Wq|Wk|Wv|Wo into one block) ----------
__global__ __launch_bounds__(256) void convert_k(
    const float* __restrict__ x,
    const float* __restrict__ Wq, const float* __restrict__ Wk,
    const float* __restrict__ Wv, const float* __restrict__ Wo,
    unsigned short* __restrict__ xb, unsigned short* __restrict__ wall)
{
    size_t e = ((size_t)blockIdx.x * 256 + threadIdx.x) << 3;
    const float* s; unsigned short* d;
    if (e < (size_t)Mm * Hh) {
        s = x + e; d = xb + e;
    } else {
        size_t f = e - (size_t)Mm * Hh;
        int t = (int)(f >> 20);
        const float* w = (t == 0) ? Wq : (t == 1) ? Wk : (t == 2) ? Wv : Wo;
        s = w + (f & 1048575);
        d = wall + f;
    }
    float4 a = *(const float4*)s;
    float4 b = *(const float4*)(s + 4);
    ushort8 o;
    o[0] = f2bf(a.x); o[1] = f2bf(a.y); o[2] = f2bf(a.z); o[3] = f2bf(a.w);
    o[4] = f2bf(b.x); o[5] = f2bf(b.y); o[6] = f2bf(b.z); o[7] = f2bf(b.w);
    *(ushort8*)d = o;
}

// ---------------- bf16 mask build: maskbf[bz*Ss+s] = mask ? 1.0bf : 0 -----------
__global__ __launch_bounds__(256) void maskbf_k(
    const int* __restrict__ am, unsigned short* __restrict__ maskbf)
{
    int i = blockIdx.x * 256 + threadIdx.x;   // 4096 total
    maskbf[i] = am[i] ? (unsigned short)0x3F80 : (unsigned short)0;
}

// ---------------- bf16 MFMA GEMM core (unchanged) --------------------------------
#define GEMM_BODY(ATYPE_PTR, WPTR, K0MAX)                                          \
    __shared__ unsigned short As[128 * 64];                                        \
    __shared__ unsigned short Bs[128 * 64];                                        \
    const int tid  = threadIdx.x;                                                  \
    const int lane = tid & 63;                                                     \
    const int w    = tid >> 6;                                                     \
    const int wr   = w >> 1, wc = w & 1;                                           \
    const int l16  = lane & 15, g = lane >> 4;                                     \
    const int R0   = blockIdx.x * 128;                                             \
    char* asb = (char*)As; char* bsb = (char*)Bs;                                  \
    f32x4 acc[4][4] = {};                                                          \
    for (int k0 = 0; k0 < K0MAX; k0 += 64) {                                       \
        _Pragma("unroll")                                                          \
        for (int it = 0; it < 4; ++it) {                                           \
            int sbase = w * 4096 + it * 1024;                                      \
            int boff  = sbase + lane * 16;                                         \
            int r     = boff >> 7;                                                 \
            int c     = (boff >> 4) & 7;                                           \
            int col   = k0 + ((c ^ (r & 7)) << 3);                                 \
            gload16(&ATYPE_PTR[(size_t)(R0 + r) * 1024 + col], asb + sbase);       \
            gload16(&WPTR[(size_t)(gn + r) * 1024 + col], bsb + sbase);            \
        }                                                                          \
        __syncthreads();                                                           \
        short8 bfrag[4][2];                                                        \
        _Pragma("unroll")                                                          \
        for (int u = 0; u < 4; ++u) {                                              \
            int row = wc * 64 + u * 16 + l16;                                      \
            _Pragma("unroll")                                                      \
            for (int s = 0; s < 2; ++s)                                            \
                bfrag[u][s] = *(const short8*)(bsb + row * 128 +                   \
                               ((s * 64 + g * 16) ^ ((row & 7) << 4)));            \
        }                                                                          \
        _Pragma("unroll")                                                          \
        for (int t = 0; t < 4; ++t) {                                              \
            int row = wr * 64 + t * 16 + l16;                                      \
            short8 af[2];                                                          \
            _Pragma("unroll")                                                      \
            for (int s = 0; s < 2; ++s)                                            \
                af[s] = *(const short8*)(asb + row * 128 +                         \
                         ((s * 64 + g * 16) ^ ((row & 7) << 4)));                  \
            _Pragma("unroll")                                                      \
            for (int u = 0; u < 4; ++u) {                                          \
                acc[t][u] = __builtin_amdgcn_mfma_f32_16x16x32_bf16(af[0], bfrag[u][0], acc[t][u], 0, 0, 0); \
                acc[t][u] = __builtin_amdgcn_mfma_f32_16x16x32_bf16(af[1], bfrag[u][1], acc[t][u], 0, 0, 0); \
            }                                                                      \
        }                                                                          \
        __syncthreads();                                                           \
    }

__global__ __launch_bounds__(256) void gemm_qkv_k(
    const unsigned short* __restrict__ xb, const unsigned short* __restrict__ wall,
    const float* __restrict__ bq, const float* __restrict__ bk, const float* __restrict__ bv,
    unsigned short* __restrict__ q, unsigned short* __restrict__ k2,
    unsigned short* __restrict__ v)
{
    const int gn = blockIdx.y * 128;
    GEMM_BODY(xb, wall, 1024)

    const int sel = gn >> 10;
    const int n0  = gn & 1023;
    const float* bias = (sel == 0) ? bq : (sel == 1) ? bk : bv;
    unsigned short* outp = (sel == 0) ? q : (sel == 1) ? k2 : v;
    // Pre-scale q by (1/8)*log2e: q feeds only QK^T; scale commutes with RoPE.
    const float qs = (sel == 0) ? 0.18033688011112042f : 1.0f;
    #pragma unroll
    for (int u = 0; u < 4; ++u) {
        int coll = wc * 64 + u * 16 + l16;
        float bb = bias[n0 + coll];
        #pragma unroll
        for (int t = 0; t < 4; ++t)
            #pragma unroll
            for (int rr = 0; rr < 4; ++rr) {
                int row = R0 + wr * 64 + t * 16 + g * 4 + rr;
                outp[(size_t)row * 1024 + n0 + coll] = f2bf((acc[t][u][rr] + bb) * qs);
            }
    }
}

__global__ __launch_bounds__(256) void gemm_out_k(
    const unsigned short* __restrict__ ao, const unsigned short* __restrict__ wo,
    const float* __restrict__ bo, float* __restrict__ out)
{
    const int gn = blockIdx.y * 128;
    GEMM_BODY(ao, wo, 1024)

    #pragma unroll
    for (int u = 0; u < 4; ++u) {
        int coll = wc * 64 + u * 16 + l16;
        float bb = bo[gn + coll];
        #pragma unroll
        for (int t = 0; t < 4; ++t)
            #pragma unroll
            for (int rr = 0; rr < 4; ++rr) {
                int row = R0 + wr * 64 + t * 16 + g * 4 + rr;
                out[(size_t)row * 1024 + gn + coll] = acc[t][u][rr] + bb;
            }
    }
}

// ---------------- RoPE + fragment materialization for q and k --------------------
__global__ __launch_bounds__(256) void rope_frag_k(
    const unsigned short* __restrict__ qin, const unsigned short* __restrict__ kin,
    unsigned short* __restrict__ qfrag, unsigned short* __restrict__ kfrag)
{
    __shared__ unsigned short Ld[2][64][72];
    const int kt = blockIdx.x;        // 0..31
    const int hp = blockIdx.y;        // 0..7
    const int zz = blockIdx.z;        // bit0 = bz, bit1 = sel
    const int bz = zz & 1, sel = zz >> 1;
    const unsigned short* src = sel ? kin : qin;
    unsigned short* dstf = sel ? kfrag : qfrag;

    const int t   = threadIdx.x;
    const int r   = t & 63;
    const int c16 = (t >> 6) << 4;    // 0,16,32,48
    const int pos = kt * 64 + r;
    const size_t rowb = (size_t)(bz * Ss + pos) * 1024;

    ushort8 A0 = *(const ushort8*)&src[rowb + hp * 64 + c16];
    ushort8 A1 = *(const ushort8*)&src[rowb + hp * 64 + c16 + 8];
    ushort8 B0 = *(const ushort8*)&src[rowb + (hp + 8) * 64 + c16];
    ushort8 B1 = *(const ushort8*)&src[rowb + (hp + 8) * 64 + c16 + 8];

    #pragma unroll
    for (int i = 0; i < 16; ++i) {
        int d = c16 + i;
        float jj  = (float)(hp * 64 + d);
        float inv = exp2f(jj * -0.0259525632621414f);   // 10000^(-j/512)
        float ang = (float)pos * inv;
        float sn, cs;
        __sincosf(ang, &sn, &cs);
        unsigned short ua = (i < 8) ? A0[i] : A1[i - 8];
        unsigned short ub = (i < 8) ? B0[i] : B1[i - 8];
        float a = bf2f(ua), b = bf2f(ub);
        Ld[0][r][d] = f2bf(a * cs - b * sn);   // head hp   (low half j)
        Ld[1][r][d] = f2bf(b * cs + a * sn);   // head hp+8 (high half j+512)
    }
    __syncthreads();

    #pragma unroll
    for (int cc = 0; cc < 4; ++cc) {
        int c    = t * 4 + cc;            // 0..1023
        int hh   = c >> 9;                // head select
        int ci   = c & 511;               // chunk within head tile (0..511)
        int blk  = ci >> 7, s2 = (ci >> 6) & 1, lane2 = ci & 63;
        int gg = lane2 >> 4, ll = lane2 & 15;
        ushort8 o = *(const ushort8*)&Ld[hh][blk * 16 + ll][s2 * 32 + gg * 8];
        size_t base = (size_t)(bz * 16 + hp + hh * 8) * 131072 + (size_t)kt * 4096;
        *(ushort8*)&dstf[base + (size_t)ci * 8] = o;
    }
}

// ---------------- V fragment materialization (masked keys -> zero rows) ----------
__global__ __launch_bounds__(256) void fragify_v_k(
    const unsigned short* __restrict__ v, const int* __restrict__ mask,
    unsigned short* __restrict__ vfrag)
{
    __shared__ unsigned short Ld[64][72];
    __shared__ int Lm[64];
    const int kt = blockIdx.x, bh = blockIdx.y;   // bh = bz*16+h
    const int bz = bh >> 4, h = bh & 15;
    const int t = threadIdx.x;
    const int r = t & 63, c0 = (t >> 6) << 4;
    const unsigned short* srcp = &v[(size_t)(bz * Ss + kt * 64 + r) * 1024 + h * 64 + c0];
    *(ushort8*)&Ld[r][c0]     = *(const ushort8*)srcp;
    *(ushort8*)&Ld[r][c0 + 8] = *(const ushort8*)(srcp + 8);
    if (t < 64) Lm[t] = mask[bz * Ss + kt * 64 + t];
    __syncthreads();

    #pragma unroll
    for (int cc = 0; cc < 2; ++cc) {
        int c = t * 2 + cc;               // 0..511
        int dt4 = c >> 7, ks = (c >> 6) & 1, lane2 = c & 63;
        int gg = lane2 >> 4, ll = lane2 & 15;
        ushort8 o;
        #pragma unroll
        for (int e = 0; e < 8; ++e) {
            int key = ks * 32 + gg * 8 + e;
            o[e] = Lm[key] ? Ld[key][dt4 * 16 + ll] : (unsigned short)0;
        }
        *(ushort8*)&vfrag[(size_t)bh * 131072 + (size_t)kt * 4096 + (size_t)c * 8] = o;
    }
}

// ---------------- Flash attention: all-register, split-K, mask-in-MFMA -----------
#define FLASH_ITER(KC, KN, KT)                                                     \
    {                                                                              \
        const int ktn = kt0 + ((((KT) - kt0) + 1) & 15);                           \
        _Pragma("unroll")                                                          \
        for (int i = 0; i < 8; ++i)                                                \
            KN[i] = *(const short8*)&kfb[(size_t)ktn * 4096 + i * 512 + lane * 8]; \
        _Pragma("unroll")                                                          \
        for (int i = 0; i < 8; ++i)                                                \
            VV[i] = *(const short8*)&vfb[(size_t)(KT) * 4096 + i * 512 + lane * 8];\
        short8 mf[2];                                                              \
        mf[0] = *(const short8*)&mbz[(KT) * 64 + g * 8];                           \
        mf[1] = *(const short8*)&mbz[(KT) * 64 + 32 + g * 8];                      \
        f32x4 S[2][4];                                                             \
        _Pragma("unroll")                                                          \
        for (int t = 0; t < 2; ++t)                                                \
            _Pragma("unroll")                                                      \
            for (int k4 = 0; k4 < 4; ++k4) S[t][k4] = (f32x4)0.f;                  \
        _Pragma("unroll")                                                          \
        for (int k4 = 0; k4 < 4; ++k4)                                             \
            _Pragma("unroll")                                                      \
            for (int t = 0; t < 2; ++t) {                                          \
                S[t][k4] = __builtin_amdgcn_mfma_f32_16x16x32_bf16(                \
                    KC[k4 * 2 + 0], qf[t][0], S[t][k4], 0, 0, 0);                  \
                S[t][k4] = __builtin_amdgcn_mfma_f32_16x16x32_bf16(                \
                    KC[k4 * 2 + 1], qf[t][1], S[t][k4], 0, 0, 0);                  \
            }                                                                      \
        float rm[2];                                                               \
        _Pragma("unroll")                                                          \
        for (int t = 0; t < 2; ++t) {                                              \
            float m0 = fmaxf(fmaxf(S[t][0][0], S[t][0][1]), fmaxf(S[t][0][2], S[t][0][3])); \
            float m1 = fmaxf(fmaxf(S[t][1][0], S[t][1][1]), fmaxf(S[t][1][2], S[t][1][3])); \
            float m2 = fmaxf(fmaxf(S[t][2][0], S[t][2][1]), fmaxf(S[t][2][2], S[t][2][3])); \
            float m3 = fmaxf(fmaxf(S[t][3][0], S[t][3][1]), fmaxf(S[t][3][2], S[t][3][3])); \
            float m  = fmaxf(fmaxf(m0, m1), fmaxf(m2, m3));                        \
            m = fmaxf(m, __shfl_xor(m, 16));                                       \
            m = fmaxf(m, __shfl_xor(m, 32));                                       \
            rm[t] = m;                                                             \
        }                                                                          \
        bool grow = (rm[0] > mrow[0] + 10.0f) || (rm[1] > mrow[1] + 10.0f);        \
        if (__any((int)grow)) {                                                    \
            float mn0 = fmaxf(mrow[0], rm[0]);                                     \
            float mn1 = fmaxf(mrow[1], rm[1]);                                     \
            float rs0 = exp2f(mrow[0] - mn0);                                      \
            float rs1 = exp2f(mrow[1] - mn1);                                      \
            mrow[0] = mn0; mrow[1] = mn1;                                          \
            _Pragma("unroll")                                                      \
            for (int r = 0; r < 4; ++r) {                                          \
                float f0 = __shfl(rs0, g * 4 + r);                                 \
                float f1 = __shfl(rs1, g * 4 + r);                                 \
                _Pragma("unroll")                                                  \
                for (int dt = 0; dt < 4; ++dt) { O[0][dt][r] *= f0; O[1][dt][r] *= f1; } \
                Osum[0][r] *= f0; Osum[1][r] *= f1;                                \
            }                                                                      \
        }                                                                          \
        _Pragma("unroll")                                                          \
        for (int t = 0; t < 2; ++t) {                                              \
            unsigned int U[4][2];                                                  \
            _Pragma("unroll")                                                      \
            for (int k4 = 0; k4 < 4; ++k4) {                                       \
                float p0 = exp2f(S[t][k4][0] - mrow[t]);                           \
                float p1 = exp2f(S[t][k4][1] - mrow[t]);                           \
                float p2 = exp2f(S[t][k4][2] - mrow[t]);                           \
                float p3 = exp2f(S[t][k4][3] - mrow[t]);                           \
                asm("v_cvt_pk_bf16_f32 %0, %1, %2" : "=v"(U[k4][0]) : "v"(p0), "v"(p1)); \
                asm("v_cvt_pk_bf16_f32 %0, %1, %2" : "=v"(U[k4][1]) : "v"(p2), "v"(p3)); \
            }                                                                      \
            asm("v_permlane32_swap_b32 %0, %1" : "+v"(U[0][0]), "+v"(U[1][0]));    \
            asm("v_permlane32_swap_b32 %0, %1" : "+v"(U[0][1]), "+v"(U[1][1]));    \
            asm("v_permlane32_swap_b32 %0, %1" : "+v"(U[2][0]), "+v"(U[3][0]));    \
            asm("v_permlane32_swap_b32 %0, %1" : "+v"(U[2][1]), "+v"(U[3][1]));    \
            asm("v_permlane16_swap_b32 %0, %1" : "+v"(U[0][0]), "+v"(U[1][0]));    \
            asm("v_permlane16_swap_b32 %0, %1" : "+v"(U[0][1]), "+v"(U[1][1]));    \
            asm("v_permlane16_swap_b32 %0, %1" : "+v"(U[2][0]), "+v"(U[3][0]));    \
            asm("v_permlane16_swap_b32 %0, %1" : "+v"(U[2][1]), "+v"(U[3][1]));    \
            _Pragma("unroll")                                                      \
            for (int ks = 0; ks < 2; ++ks) {                                       \
                u32x4 gp;                                                          \
                gp[0] = U[2 * ks][0]; gp[1] = U[2 * ks][1];                        \
                gp[2] = U[2 * ks + 1][0]; gp[3] = U[2 * ks + 1][1];                \
                short8 pf = __builtin_bit_cast(short8, gp);                        \
                Osum[t] = __builtin_amdgcn_mfma_f32_16x16x32_bf16(pf, mf[ks], Osum[t], 0, 0, 0); \
                _Pragma("unroll")                                                  \
                for (int dt = 0; dt < 4; ++dt)                                     \
                    O[t][dt] = __builtin_amdgcn_mfma_f32_16x16x32_bf16(            \
                        pf, VV[dt * 2 + ks], O[t][dt], 0, 0, 0);                   \
            }                                                                      \
        }                                                                          \
    }

__global__ __launch_bounds__(256, 2) void flash_k(
    const unsigned short* __restrict__ qfrag, const unsigned short* __restrict__ kfrag,
    const unsigned short* __restrict__ vfrag, const unsigned short* __restrict__ maskbf,
    unsigned short* __restrict__ opart, float2* __restrict__ ml)
{
    // Bijective XCD remap: 1024 blocks = 8 XCDs x (4 (h,bz) groups x 16 qb x 2 half).
    const int F   = blockIdx.x;
    const int xcd = F & 7, j = F >> 3;          // j: 0..127
    const int grp = xcd * 4 + (j >> 5);         // 0..31
    const int rem = j & 31;
    const int qb  = rem >> 1;
    const int half = rem & 1;
    const int h   = grp & 15;
    const int bz  = grp >> 4;
    const int kt0 = half * 16;

    const int tid  = threadIdx.x;
    const int lane = tid & 63;
    const int w    = tid >> 6;
    const int l16  = lane & 15;
    const int g    = lane >> 4;

    const size_t fb = (size_t)(bz * 16 + h) * 131072;
    const unsigned short* kfb = kfrag + fb;
    const unsigned short* vfb = vfrag + fb;
    const unsigned short* qfb = qfrag + fb;
    const unsigned short* mbz = maskbf + bz * Ss;

    // Q fragments (pre-scaled): blk16 = qb*8 + w*2 + t
    short8 qf[2][2];
    #pragma unroll
    for (int t = 0; t < 2; ++t)
        #pragma unroll
        for (int s = 0; s < 2; ++s)
            qf[t][s] = *(const short8*)&qfb[(size_t)(qb * 8 + w * 2 + t) * 1024
                                            + s * 512 + lane * 8];

    f32x4 O[2][4];
    #pragma unroll
    for (int t = 0; t < 2; ++t)
        #pragma unroll
        for (int d = 0; d < 4; ++d) O[t][d] = (f32x4)0.f;
    f32x4 Osum[2];
    Osum[0] = (f32x4)0.f; Osum[1] = (f32x4)0.f;
    float mrow[2] = {-1.0e4f, -1.0e4f};

    short8 KA[8], KB[8], VV[8];
    #pragma unroll
    for (int i = 0; i < 8; ++i)
        KA[i] = *(const short8*)&kfb[(size_t)kt0 * 4096 + i * 512 + lane * 8];

    for (int kt2 = 0; kt2 < 16; kt2 += 2) {
        FLASH_ITER(KA, KB, kt0 + kt2)
        FLASH_ITER(KB, KA, kt0 + kt2 + 1)
    }

    // ---- epilogue: normalized partial O (bf16) + per-query (m, sum) ----
    const size_t NE = (size_t)Mm * Hh;
    #pragma unroll
    for (int t = 0; t < 2; ++t)
        #pragma unroll
        for (int r = 0; r < 4; ++r) {
            float osum = Osum[t][r];
            float inv  = osum > 0.f ? 1.0f / osum : 0.f;
            float mo   = __shfl(mrow[t], g * 4 + r);   // S-layout m -> O-layout
            int rowl   = qb * 128 + w * 32 + t * 16 + g * 4 + r;   // 0..2047
            size_t ob  = (size_t)half * NE
                       + ((size_t)(bz * Ss + rowl)) * 1024 + h * 64;
            #pragma unroll
            for (int dt = 0; dt < 4; ++dt)
                opart[ob + dt * 16 + l16] = f2bf(O[t][dt][r] * inv);
            if (l16 == 0)
                ml[((half * 2 + bz) * 16 + h) * 2048 + rowl] = make_float2(mo, osum);
        }
}

// ---------------- Combine split-K halves -----------------------------------------
__global__ __launch_bounds__(256) void combine_k(
    const unsigned short* __restrict__ opart, const float2* __restrict__ ml,
    unsigned short* __restrict__ ao)
{
    const size_t NE = (size_t)Mm * Hh;
    int c    = blockIdx.x * 256 + threadIdx.x;   // 0..524287 (4096 rows x 128)
    int row  = c >> 7;                           // bz*2048 + qrow
    int col8 = c & 127;
    int h    = col8 >> 3;
    int bz   = row >> 11, qrow = row & 2047;

    float2 a = ml[((0 * 2 + bz) * 16 + h) * 2048 + qrow];
    float2 b = ml[((1 * 2 + bz) * 16 + h) * 2048 + qrow];
    float M  = fmaxf(a.x, b.x);
    float w1 = exp2f(a.x - M) * a.y;
    float w2 = exp2f(b.x - M) * b.y;
    float tot = w1 + w2;
    float inv = tot > 0.f ? 1.0f / tot : 0.f;
    w1 *= inv; w2 *= inv;

    ushort8 o1 = *(const ushort8*)&opart[(size_t)c * 8];
    ushort8 o2 = *(const ushort8*)&opart[NE + (size_t)c * 8];
    ushort8 o;
    #pragma unroll
    for (int jj = 0; jj < 8; ++jj)
        o[jj] = f2bf(bf2f(o1[jj]) * w1 + bf2f(o2[jj]) * w2);
    *(ushort8*)&ao[(size_t)c * 8] = o;
}

extern "C" void kernel_launch(void* const* d_in, const int* in_sizes, int n_in,
                              void* d_out, int out_size, void* d_ws, size_t ws_size,
                              hipStream_t stream)
{
    const float* x  = (const float*)d_in[0];
    const int*   am = (const int*)d_in[1];
    const float* Wq = (const float*)d_in[2];
    const float* bq = (const float*)d_in[3];
    const float* Wk = (const float*)d_in[4];
    const float* bk = (const float*)d_in[5];
    const float* Wv = (const float*)d_in[6];
    const float* bv = (const float*)d_in[7];
    const float* Wo = (const float*)d_in[8];
    const float* bo = (const float*)d_in[9];
    float* out = (float*)d_out;

    const size_t NE = (size_t)Mm * Hh;           // 4M elems
    unsigned short* q     = (unsigned short*)d_ws;
    unsigned short* k     = q + NE;
    unsigned short* v     = k + NE;
    unsigned short* ao    = v + NE;
    unsigned short* xb    = ao + NE;             // gemm input; reused as qfrag
    unsigned short* wall  = xb + NE;             // [Wq;Wk;Wv;Wo] rows
    unsigned short* wo    = wall + 3u * 1048576u;
    unsigned short* kfrag = wall + 4u * 1048576u;
    unsigned short* qfrag = xb;                  // xb dead after gemm_qkv
    unsigned short* vfrag = q;                   // q dead after rope_frag
    unsigned short* opart = k;                   // k,v dead once frags built (16 MB)
    float2*         ml    = (float2*)(kfrag + 4u * 1048576u);   // 1 MB, 131072 entries
    unsigned short* maskbf = (unsigned short*)(ml + 131072);    // AFTER ml's full extent

    convert_k<<<(2 * NE) / (256 * 8), 256, 0, stream>>>(x, Wq, Wk, Wv, Wo, xb, wall);
    maskbf_k<<<dim3(Mm / 256), 256, 0, stream>>>(am, maskbf);
    gemm_qkv_k<<<dim3(Mm / 128, 3072 / 128), 256, 0, stream>>>(
        xb, wall, bq, bk, bv, q, k, v);
    rope_frag_k<<<dim3(32, 8, 4), 256, 0, stream>>>(q, k, qfrag, kfrag);
    fragify_v_k<<<dim3(32, 32), 256, 0, stream>>>(v, am, vfrag);
    flash_k<<<dim3(1024), 256, 0, stream>>>(qfrag, kfrag, vfrag, maskbf, opart, ml);
    combine_k<<<dim3((Mm * 128) / 256), 256, 0, stream>>>(opart, ml, ao);
    gemm_out_k<<<dim3(Mm / 128, Hh / 128), 256, 0, stream>>>(ao, wo, bo, out);
}